// Round 2
// baseline (12453.296 us; speedup 1.0000x reference)
//
#include <hip/hip_runtime.h>

#define B_   16
#define T_   365
#define P_   10
#define NI_  8
#define EP_  90
#define EI_  80
#define PD_  10
#define ID_  8
#define ED_  10
#define H_   128
#define LH_  256
#define DH_  64
#define BT_  (B_*T_)          // 5840
#define NPROW_ (BT_*P_)       // 58400
#define NIROW_ (BT_*NI_)      // 46720

// ---------------------------------------------------------------------------
// Node encoders: h_p = relu(pf@Wpe+bpe), h_i = relu(jf@Wie+bie)
// ---------------------------------------------------------------------------
__global__ __launch_bounds__(128) void k_enc(
    const float* __restrict__ pf, const float* __restrict__ jf,
    const float* __restrict__ Wpe, const float* __restrict__ bpe,
    const float* __restrict__ Wie, const float* __restrict__ bie,
    float* __restrict__ hp, float* __restrict__ hi)
{
    const int r = blockIdx.x;
    const int j = threadIdx.x;
    __shared__ float xs[16];
    if (r < NPROW_) {
        if (j < PD_) xs[j] = pf[(size_t)r*PD_ + j];
        __syncthreads();
        float acc = bpe[j];
        #pragma unroll
        for (int k = 0; k < PD_; k++) acc += xs[k]*Wpe[k*H_ + j];
        hp[(size_t)r*H_ + j] = fmaxf(acc, 0.f);
    } else {
        const int r2 = r - NPROW_;
        if (j < ID_) xs[j] = jf[(size_t)r2*ID_ + j];
        __syncthreads();
        float acc = bie[j];
        #pragma unroll
        for (int k = 0; k < ID_; k++) acc += xs[k]*Wie[k*H_ + j];
        hi[(size_t)r2*H_ + j] = fmaxf(acc, 0.f);
    }
}

// ---------------------------------------------------------------------------
// Fused GNN layer: one block per (b,t). Everything in LDS, no global atomics.
// ---------------------------------------------------------------------------
__device__ __forceinline__ void edge_block(
    int bt, int tid, int NE,
    const float* __restrict__ ef,     // edge feats, row stride NE*ED_
    const int*   __restrict__ eidx,   // (2,NE)
    const float* __restrict__ Wenc, const float* __restrict__ benc,
    const float* __restrict__ Wbot,   // 128x128
    const float* __restrict__ sproj,  // LDS: hpp_s or hip_s
    float* __restrict__ agg_s,        // LDS: 10x128, pre-zeroed
    float* __restrict__ ee_s, float* __restrict__ w_s,
    float* __restrict__ xr_s, int* __restrict__ src_s, int* __restrict__ dst_s)
{
    for (int e = tid; e < NE; e += 512) { src_s[e] = eidx[e]; dst_s[e] = eidx[NE + e]; }
    __syncthreads();

    const int c0 = (tid & 31) * 4;    // 4 cols
    const int r0 = (tid >> 5) * 2;    // 2 rows

    for (int rt = 0; rt < NE; rt += 32) {
        const int RT = (NE - rt < 32) ? (NE - rt) : 32;
        // raw edge feature tile
        for (int i = tid; i < RT*ED_; i += 512)
            xr_s[i] = ef[(size_t)bt*NE*ED_ + rt*ED_ + i];
        __syncthreads();
        // edge encoder: eenc = relu(xr @ Wenc + benc)  -> ee_s[RT][128]
        for (int o = tid; o < RT*H_; o += 512) {
            const int e = o >> 7, cc = o & 127;
            float a = benc[cc];
            #pragma unroll
            for (int k = 0; k < ED_; k++) a += xr_s[e*ED_ + k]*Wenc[k*H_ + cc];
            ee_s[o] = fmaxf(a, 0.f);
        }
        __syncthreads();
        // GEMM: (RT x 128) @ (128 x 128)
        float acc0[4] = {0.f,0.f,0.f,0.f};
        float acc1[4] = {0.f,0.f,0.f,0.f};
        for (int kc = 0; kc < 4; kc++) {
            for (int i = tid; i < 32*H_; i += 512) {
                const int kk = i >> 7, cc = i & 127;
                w_s[i] = Wbot[(kc*32 + kk)*H_ + cc];
            }
            __syncthreads();
            #pragma unroll 8
            for (int j = 0; j < 32; j++) {
                const float4 wv = *(const float4*)&w_s[j*H_ + c0];
                const float a0 = ee_s[(r0    )*H_ + kc*32 + j];
                const float a1 = ee_s[(r0 + 1)*H_ + kc*32 + j];
                acc0[0] += a0*wv.x; acc0[1] += a0*wv.y; acc0[2] += a0*wv.z; acc0[3] += a0*wv.w;
                acc1[0] += a1*wv.x; acc1[1] += a1*wv.y; acc1[2] += a1*wv.z; acc1[3] += a1*wv.w;
            }
            __syncthreads();
        }
        // epilogue: m = relu(acc + sproj[src]) written back in-place over ee_s
        #pragma unroll
        for (int i = 0; i < 2; i++) {
            const int r = r0 + i;
            if (r < RT) {
                const int sidx = src_s[rt + r];
                const float* hr = sproj + sidx*H_ + c0;
                const float* a = (i == 0) ? acc0 : acc1;
                float4 v;
                v.x = fmaxf(a[0] + hr[0], 0.f);
                v.y = fmaxf(a[1] + hr[1], 0.f);
                v.z = fmaxf(a[2] + hr[2], 0.f);
                v.w = fmaxf(a[3] + hr[3], 0.f);
                *(float4*)&ee_s[r*H_ + c0] = v;
            }
        }
        __syncthreads();
        // aggregate into agg_s via LDS atomics
        {
            const int cc = tid & 127, gg = tid >> 7;
            for (int e = gg; e < RT; e += 4)
                atomicAdd(&agg_s[dst_s[rt + e]*H_ + cc], ee_s[e*H_ + cc]);
        }
        __syncthreads();
    }
}

__global__ __launch_bounds__(512) void k_layer(
    int l,
    const float* __restrict__ hp_in, const float* __restrict__ hi_g,
    const int* __restrict__ ip2p, const int* __restrict__ ii2p,
    const float* __restrict__ epf, const float* __restrict__ eif,
    const float* __restrict__ Wep, const float* __restrict__ bep,
    const float* __restrict__ Wei, const float* __restrict__ bei,
    const float* __restrict__ Wmp, const float* __restrict__ bmp,
    const float* __restrict__ Wmi, const float* __restrict__ bmi,
    const float* __restrict__ Wu,  const float* __restrict__ bu,
    float* __restrict__ hp_out)
{
    const int bt  = blockIdx.x;
    const int tid = threadIdx.x;

    __shared__ float hp_s [P_*H_];   // 1280
    __shared__ float hi_s [NI_*H_];  // 1024
    __shared__ float hpp_s[P_*H_];
    __shared__ float hip_s[NI_*H_];
    __shared__ float ee_s [32*H_];   // 4096 (edge tile / scratch)
    __shared__ float w_s  [32*H_];   // 4096 (W chunk / scratch)
    __shared__ float aggp_s[P_*H_];
    __shared__ float aggi_s[P_*H_];
    __shared__ float xr_s[32*ED_];
    __shared__ int   src_s[EP_], dst_s[EP_];

    // P0: load node states, zero aggregators
    for (int i = tid; i < P_*H_;  i += 512) hp_s[i] = hp_in[(size_t)bt*(P_*H_) + i];
    for (int i = tid; i < NI_*H_; i += 512) hi_s[i] = hi_g[(size_t)bt*(NI_*H_) + i];
    for (int i = tid; i < P_*H_;  i += 512) { aggp_s[i] = 0.f; aggi_s[i] = 0.f; }
    __syncthreads();

    const int c = tid & 127;
    const int g = tid >> 7;   // 0..3 (k-quarter)

    // P1: hpp = hp @ Wmp_top + bmp   (K=128 split over 4 groups)
    {
        const float* Wt = Wmp + (size_t)l*(2*H_*H_);
        float acc[P_];
        #pragma unroll
        for (int p = 0; p < P_; p++) acc[p] = 0.f;
        for (int j = 0; j < 32; j++) {
            const int k = g*32 + j;
            const float wv = Wt[k*H_ + c];
            #pragma unroll
            for (int p = 0; p < P_; p++) acc[p] += hp_s[p*H_ + k]*wv;
        }
        float* buf = (g < 2) ? (ee_s + g*(P_*H_)) : (w_s + (g - 2)*(P_*H_));
        #pragma unroll
        for (int p = 0; p < P_; p++) buf[p*H_ + c] = acc[p];
        __syncthreads();
        for (int o = tid; o < P_*H_; o += 512) {
            const int pp = o >> 7, cc = o & 127;
            hpp_s[o] = bmp[l*H_ + cc]
                     + ee_s[pp*H_ + cc] + ee_s[(P_ + pp)*H_ + cc]
                     + w_s [pp*H_ + cc] + w_s [(P_ + pp)*H_ + cc];
        }
        __syncthreads();
    }
    // P2: hip = hi @ Wmi_top + bmi
    {
        const float* Wt = Wmi + (size_t)l*(2*H_*H_);
        float acc[NI_];
        #pragma unroll
        for (int p = 0; p < NI_; p++) acc[p] = 0.f;
        for (int j = 0; j < 32; j++) {
            const int k = g*32 + j;
            const float wv = Wt[k*H_ + c];
            #pragma unroll
            for (int p = 0; p < NI_; p++) acc[p] += hi_s[p*H_ + k]*wv;
        }
        float* buf = ee_s + g*(NI_*H_);
        #pragma unroll
        for (int p = 0; p < NI_; p++) buf[p*H_ + c] = acc[p];
        __syncthreads();
        for (int o = tid; o < NI_*H_; o += 512) {
            const int pp = o >> 7, cc = o & 127;
            hip_s[o] = bmi[l*H_ + cc]
                     + ee_s[pp*H_ + cc]         + ee_s[1024 + pp*H_ + cc]
                     + ee_s[2048 + pp*H_ + cc]  + ee_s[3072 + pp*H_ + cc];
        }
        __syncthreads();
    }

    // P3-5: p2p edges -> aggp_s ; P6-8: i2p edges -> aggi_s
    edge_block(bt, tid, EP_, epf, ip2p, Wep, bep,
               Wmp + (size_t)l*(2*H_*H_) + H_*H_, hpp_s, aggp_s,
               ee_s, w_s, xr_s, src_s, dst_s);
    edge_block(bt, tid, EI_, eif, ii2p, Wei, bei,
               Wmi + (size_t)l*(2*H_*H_) + H_*H_, hip_s, aggi_s,
               ee_s, w_s, xr_s, src_s, dst_s);

    // P9: update h_p = relu([hp|aggp|aggi] @ Wu + bu)  (K=384 over 4 groups)
    {
        const float* Wl = Wu + (size_t)l*(3*H_*H_);
        float acc[P_];
        #pragma unroll
        for (int p = 0; p < P_; p++) acc[p] = 0.f;
        #pragma unroll
        for (int seg = 0; seg < 3; seg++) {
            const float* As = (seg == 0) ? hp_s : ((seg == 1) ? aggp_s : aggi_s);
            const int klo0 = seg*H_       > g*96       ? seg*H_       : g*96;
            const int khi0 = seg*H_ + H_  < g*96 + 96  ? seg*H_ + H_  : g*96 + 96;
            for (int k = klo0; k < khi0; k++) {
                const float wv = Wl[k*H_ + c];
                #pragma unroll
                for (int p = 0; p < P_; p++) acc[p] += As[p*H_ + (k - seg*H_)]*wv;
            }
        }
        float* buf = (g < 2) ? (ee_s + g*(P_*H_)) : (w_s + (g - 2)*(P_*H_));
        #pragma unroll
        for (int p = 0; p < P_; p++) buf[p*H_ + c] = acc[p];
        __syncthreads();
        for (int o = tid; o < P_*H_; o += 512) {
            const int pp = o >> 7, cc = o & 127;
            const float v = bu[l*H_ + cc]
                          + ee_s[pp*H_ + cc] + ee_s[(P_ + pp)*H_ + cc]
                          + w_s [pp*H_ + cc] + w_s [(P_ + pp)*H_ + cc];
            hp_out[(size_t)bt*(P_*H_) + o] = fmaxf(v, 0.f);
        }
    }
}

// ---------------------------------------------------------------------------
// xproj0 = emb @ Wx0 + lb0   (5840 x 1280 x 1024), tiled fp32 GEMM
// ---------------------------------------------------------------------------
__global__ __launch_bounds__(256) void k_gemm_xp(
    const float* __restrict__ A, const float* __restrict__ W,
    const float* __restrict__ bias, float* __restrict__ C)
{
    const int m0 = blockIdx.x*32;
    const int n0 = blockIdx.y*128;
    const int tid = threadIdx.x;
    __shared__ float As[32*32];
    __shared__ float Ws[32*128];
    const int c0 = (tid & 31)*4;
    const int r0 = (tid >> 5)*4;
    float acc[4][4] = {};
    for (int kc = 0; kc < 1280; kc += 32) {
        for (int i = tid; i < 1024; i += 256) {
            const int r = i >> 5, k = i & 31, row = m0 + r;
            As[i] = (row < BT_) ? A[(size_t)row*1280 + kc + k] : 0.f;
        }
        for (int i = tid; i < 4096; i += 256) {
            const int kk = i >> 7, cc = i & 127;
            Ws[i] = W[(size_t)(kc + kk)*1024 + n0 + cc];
        }
        __syncthreads();
        #pragma unroll 8
        for (int j = 0; j < 32; j++) {
            const float4 wv = *(const float4*)&Ws[j*128 + c0];
            const float a0 = As[(r0    )*32 + j];
            const float a1 = As[(r0 + 1)*32 + j];
            const float a2 = As[(r0 + 2)*32 + j];
            const float a3 = As[(r0 + 3)*32 + j];
            acc[0][0]+=a0*wv.x; acc[0][1]+=a0*wv.y; acc[0][2]+=a0*wv.z; acc[0][3]+=a0*wv.w;
            acc[1][0]+=a1*wv.x; acc[1][1]+=a1*wv.y; acc[1][2]+=a1*wv.z; acc[1][3]+=a1*wv.w;
            acc[2][0]+=a2*wv.x; acc[2][1]+=a2*wv.y; acc[2][2]+=a2*wv.z; acc[2][3]+=a2*wv.w;
            acc[3][0]+=a3*wv.x; acc[3][1]+=a3*wv.y; acc[3][2]+=a3*wv.z; acc[3][3]+=a3*wv.w;
        }
        __syncthreads();
    }
    #pragma unroll
    for (int i = 0; i < 4; i++) {
        const int row = m0 + r0 + i;
        if (row < BT_) {
            float4 o;
            o.x = acc[i][0] + bias[n0 + c0 + 0];
            o.y = acc[i][1] + bias[n0 + c0 + 1];
            o.z = acc[i][2] + bias[n0 + c0 + 2];
            o.w = acc[i][3] + bias[n0 + c0 + 3];
            *(float4*)&C[(size_t)row*1024 + n0 + c0] = o;
        }
    }
}

// ---------------------------------------------------------------------------
// Persistent 2-layer LSTM scan. 64 WGs: 0-31 = layer0 slices, 32-63 = layer1.
// Each WG owns 8 h-columns (32 gate cols), Wh slice in registers.
// h exchanged via global [t][k][b] history buffers + per-WG epoch flags.
// ---------------------------------------------------------------------------
__device__ __forceinline__ float sigm(float x) { return 1.f/(1.f + expf(-x)); }

__global__ __launch_bounds__(512) void k_lstm_scan(
    const float* __restrict__ xproj0,                    // [5840][1024] (lb0 folded)
    const float* __restrict__ Wh0,
    const float* __restrict__ Wx1, const float* __restrict__ Wh1,
    const float* __restrict__ lb1,
    float* __restrict__ h1_ex, float* __restrict__ h2_ex, // [366][256][16]
    float* __restrict__ h2_out,                           // [5840][256]
    int* __restrict__ flag0, int* __restrict__ flag1)
{
    const int tid   = threadIdx.x;
    const int layer = blockIdx.x >> 5;
    const int s     = blockIdx.x & 31;
    const int cc    = tid & 31;          // local gate col
    const int g     = tid >> 5;          // k-group 0..15
    const int gcol  = (cc >> 3)*256 + s*8 + (cc & 7);

    __shared__ float pool[8192];         // h stage  /  reduction scratch (aliased)
    __shared__ float z_s[512];

    float w[32];
    if (layer == 0) {
        #pragma unroll
        for (int j = 0; j < 16; j++) w[j] = Wh0[(size_t)(g*16 + j)*1024 + gcol];
    } else {
        #pragma unroll
        for (int j = 0; j < 32; j++) {
            const int k = g*32 + j;
            w[j] = (k < 256) ? Wx1[(size_t)k*1024 + gcol]
                             : Wh1[(size_t)(k - 256)*1024 + gcol];
        }
    }

    const int kl2 = tid >> 4, b2 = tid & 15;   // gate threads (tid<128)
    const int oc  = tid >> 4, ob = tid & 15;   // combine mapping (tid<512)
    const int gcol_o = (oc >> 3)*256 + s*8 + (oc & 7);
    const float xv_l1 = lb1[gcol_o];
    float cst = 0.f;

    for (int t = 0; t < T_; t++) {
        // x contribution (prefetched before spin; independent of flags)
        float xv = (layer == 0) ? xproj0[((size_t)ob*T_ + t)*1024 + gcol_o] : xv_l1;

        // wait for producers
        if (layer == 0) {
            if (tid < 32)
                while (__hip_atomic_load(&flag0[tid], __ATOMIC_RELAXED, __HIP_MEMORY_SCOPE_AGENT) < t)
                    __builtin_amdgcn_s_sleep(1);
        } else {
            if (tid < 32) {
                while (__hip_atomic_load(&flag0[tid], __ATOMIC_RELAXED, __HIP_MEMORY_SCOPE_AGENT) < t + 1)
                    __builtin_amdgcn_s_sleep(1);
            } else if (tid < 64) {
                while (__hip_atomic_load(&flag1[tid - 32], __ATOMIC_RELAXED, __HIP_MEMORY_SCOPE_AGENT) < t)
                    __builtin_amdgcn_s_sleep(1);
            }
        }
        __syncthreads();
        __threadfence();   // agent acquire: invalidate caches before reading peers' data

        // stage h into LDS [k][16b]
        if (layer == 0) {
            const float* src = h1_ex + (size_t)t*4096;
            for (int i = tid; i < 4096; i += 512) pool[i] = src[i];
        } else {
            const float* s1 = h1_ex + (size_t)(t + 1)*4096;
            const float* s2 = h2_ex + (size_t)t*4096;
            for (int i = tid; i < 4096; i += 512) pool[i]        = s1[i];
            for (int i = tid; i < 4096; i += 512) pool[4096 + i] = s2[i];
        }
        __syncthreads();

        float acc[16];
        #pragma unroll
        for (int i = 0; i < 16; i++) acc[i] = 0.f;
        if (layer == 0) {
            #pragma unroll
            for (int j = 0; j < 16; j++) {
                const int k = g*16 + j;
                const float4* hp4 = (const float4*)&pool[k*16];
                const float wv = w[j];
                const float4 h0 = hp4[0], h1v = hp4[1], h2v = hp4[2], h3v = hp4[3];
                acc[0]+=h0.x*wv;  acc[1]+=h0.y*wv;  acc[2]+=h0.z*wv;  acc[3]+=h0.w*wv;
                acc[4]+=h1v.x*wv; acc[5]+=h1v.y*wv; acc[6]+=h1v.z*wv; acc[7]+=h1v.w*wv;
                acc[8]+=h2v.x*wv; acc[9]+=h2v.y*wv; acc[10]+=h2v.z*wv;acc[11]+=h2v.w*wv;
                acc[12]+=h3v.x*wv;acc[13]+=h3v.y*wv;acc[14]+=h3v.z*wv;acc[15]+=h3v.w*wv;
            }
        } else {
            #pragma unroll
            for (int j = 0; j < 32; j++) {
                const int k = g*32 + j;
                const float4* hp4 = (const float4*)&pool[k*16];
                const float wv = w[j];
                const float4 h0 = hp4[0], h1v = hp4[1], h2v = hp4[2], h3v = hp4[3];
                acc[0]+=h0.x*wv;  acc[1]+=h0.y*wv;  acc[2]+=h0.z*wv;  acc[3]+=h0.w*wv;
                acc[4]+=h1v.x*wv; acc[5]+=h1v.y*wv; acc[6]+=h1v.z*wv; acc[7]+=h1v.w*wv;
                acc[8]+=h2v.x*wv; acc[9]+=h2v.y*wv; acc[10]+=h2v.z*wv;acc[11]+=h2v.w*wv;
                acc[12]+=h3v.x*wv;acc[13]+=h3v.y*wv;acc[14]+=h3v.z*wv;acc[15]+=h3v.w*wv;
            }
        }
        __syncthreads();   // all h_s reads done; pool reusable as scratch
        {
            float* red = pool + (cc*16 + g)*16;
            *(float4*)&red[0]  = make_float4(acc[0],  acc[1],  acc[2],  acc[3]);
            *(float4*)&red[4]  = make_float4(acc[4],  acc[5],  acc[6],  acc[7]);
            *(float4*)&red[8]  = make_float4(acc[8],  acc[9],  acc[10], acc[11]);
            *(float4*)&red[12] = make_float4(acc[12], acc[13], acc[14], acc[15]);
        }
        __syncthreads();
        {
            float zsum = xv;
            #pragma unroll
            for (int g2 = 0; g2 < 16; g2++) zsum += pool[(oc*16 + g2)*16 + ob];
            z_s[oc*16 + ob] = zsum;
        }
        __syncthreads();
        if (tid < 128) {
            const float zi = z_s[(     kl2)*16 + b2];
            const float zf = z_s[( 8 + kl2)*16 + b2];
            const float zg = z_s[(16 + kl2)*16 + b2];
            const float zo = z_s[(24 + kl2)*16 + b2];
            cst = sigm(zf)*cst + sigm(zi)*tanhf(zg);
            const float h = sigm(zo)*tanhf(cst);
            const size_t base = (size_t)(t + 1)*4096 + (s*8 + kl2)*16 + b2;
            if (layer == 0) h1_ex[base] = h;
            else { h2_ex[base] = h; h2_out[((size_t)b2*T_ + t)*LH_ + s*8 + kl2] = h; }
            __threadfence();   // agent release: flush before flagging
        }
        __syncthreads();
        if (tid == 0) {
            int* f = (layer == 0) ? &flag0[s] : &flag1[s];
            __hip_atomic_store(f, t + 1, __ATOMIC_RELEASE, __HIP_MEMORY_SCOPE_AGENT);
        }
    }
}

// ---------------------------------------------------------------------------
// Decoder MLP + softplus, one block per (b,t)
// ---------------------------------------------------------------------------
__global__ __launch_bounds__(64) void k_dec(
    const float* __restrict__ h2,
    const float* __restrict__ Wd1, const float* __restrict__ bd1, const float* __restrict__ a1p,
    const float* __restrict__ Wd2, const float* __restrict__ bd2, const float* __restrict__ a2p,
    const float* __restrict__ Wd3, const float* __restrict__ bd3,
    float* __restrict__ oil, float* __restrict__ water)
{
    const int r = blockIdx.x, tid = threadIdx.x;
    __shared__ float hrow[256], d1s[64], d2s[64];
    for (int i = tid; i < 256; i += 64) hrow[i] = h2[(size_t)r*256 + i];
    __syncthreads();
    const float a1 = a1p[0], a2 = a2p[0];
    float acc = bd1[tid];
    for (int k = 0; k < 256; k++) acc += hrow[k]*Wd1[k*64 + tid];
    d1s[tid] = (acc >= 0.f) ? acc : a1*acc;
    __syncthreads();
    acc = bd2[tid];
    for (int k = 0; k < 64; k++) acc += d1s[k]*Wd2[k*64 + tid];
    d2s[tid] = (acc >= 0.f) ? acc : a2*acc;
    __syncthreads();
    if (tid < 20) {
        acc = bd3[tid];
        for (int k = 0; k < 64; k++) acc += d2s[k]*Wd3[k*20 + tid];
        const float spv = (acc > 20.f) ? acc : log1pf(expf(acc));
        const int p = tid >> 1;
        if (tid & 1) water[(size_t)r*10 + p] = spv;
        else         oil  [(size_t)r*10 + p] = spv;
    }
}

// ---------------------------------------------------------------------------
extern "C" void kernel_launch(void* const* d_in, const int* in_sizes, int n_in,
                              void* d_out, int out_size, void* d_ws, size_t ws_size,
                              hipStream_t stream)
{
    const float* pf  = (const float*)d_in[0];
    const float* jf  = (const float*)d_in[1];
    const float* epf = (const float*)d_in[2];
    const float* eif = (const float*)d_in[3];
    const int*   ip2p= (const int*)d_in[4];
    const int*   ii2p= (const int*)d_in[5];
    const float* Wpe = (const float*)d_in[6];  const float* bpe = (const float*)d_in[7];
    const float* Wie = (const float*)d_in[8];  const float* bie = (const float*)d_in[9];
    const float* Wep = (const float*)d_in[10]; const float* bep = (const float*)d_in[11];
    const float* Wei = (const float*)d_in[12]; const float* bei = (const float*)d_in[13];
    const float* Wmp = (const float*)d_in[14]; const float* bmp = (const float*)d_in[15];
    const float* Wmi = (const float*)d_in[16]; const float* bmi = (const float*)d_in[17];
    const float* Wu  = (const float*)d_in[18]; const float* bu  = (const float*)d_in[19];
    const float* Wx0 = (const float*)d_in[20]; const float* Wh0 = (const float*)d_in[21];
    const float* lb0 = (const float*)d_in[22];
    const float* Wx1 = (const float*)d_in[23]; const float* Wh1 = (const float*)d_in[24];
    const float* lb1 = (const float*)d_in[25];
    const float* Wd1 = (const float*)d_in[26]; const float* bd1 = (const float*)d_in[27];
    const float* a1  = (const float*)d_in[28];
    const float* Wd2 = (const float*)d_in[29]; const float* bd2 = (const float*)d_in[30];
    const float* a2  = (const float*)d_in[31];
    const float* Wd3 = (const float*)d_in[32]; const float* bd3 = (const float*)d_in[33];

    float* oil   = (float*)d_out;
    float* water = oil + NPROW_;
    float* emb   = water + NPROW_;          // (B,T,P,H) fp32, also LSTM input

    float* ws    = (float*)d_ws;
    float* X0    = ws;                       // 7,475,200
    float* X1    = X0 + 7475200;             // 7,475,200
    float* hibuf = X1 + 7475200;             // 5,980,160
    float* xp0   = hibuf + 5980160;          // 5,980,160
    float* h1ex  = xp0 + 5980160;            // 1,499,136 (366*256*16)
    float* h2ex  = h1ex + 1499136;           // 1,499,136
    float* h2o   = h2ex + 1499136;           // 1,495,040
    int*   flag0 = (int*)(h2o + 1495040);
    int*   flag1 = flag0 + 32;

    hipMemsetAsync(flag0, 0, 64*sizeof(int), stream);
    hipMemsetAsync(h1ex, 0, 4096*sizeof(float), stream);   // h1[-1] = 0
    hipMemsetAsync(h2ex, 0, 4096*sizeof(float), stream);   // h2[-1] = 0

    k_enc<<<NPROW_ + NIROW_, 128, 0, stream>>>(pf, jf, Wpe, bpe, Wie, bie, X0, hibuf);

    k_layer<<<BT_, 512, 0, stream>>>(0, X0, hibuf, ip2p, ii2p, epf, eif,
        Wep, bep, Wei, bei, Wmp, bmp, Wmi, bmi, Wu, bu, X1);
    k_layer<<<BT_, 512, 0, stream>>>(1, X1, hibuf, ip2p, ii2p, epf, eif,
        Wep, bep, Wei, bei, Wmp, bmp, Wmi, bmi, Wu, bu, X0);
    k_layer<<<BT_, 512, 0, stream>>>(2, X0, hibuf, ip2p, ii2p, epf, eif,
        Wep, bep, Wei, bei, Wmp, bmp, Wmi, bmi, Wu, bu, emb);

    dim3 gx((BT_ + 31)/32, 8);
    k_gemm_xp<<<gx, 256, 0, stream>>>(emb, Wx0, lb0, xp0);

    k_lstm_scan<<<64, 512, 0, stream>>>(xp0, Wh0, Wx1, Wh1, lb1,
                                        h1ex, h2ex, h2o, flag0, flag1);

    k_dec<<<BT_, 64, 0, stream>>>(h2o, Wd1, bd1, a1, Wd2, bd2, a2, Wd3, bd3, oil, water);
}

// Round 3
// 9688.258 us; speedup vs baseline: 1.2854x; 1.2854x over previous
//
#include <hip/hip_runtime.h>

#define B_   16
#define T_   365
#define P_   10
#define NI_  8
#define EP_  90
#define EI_  80
#define PD_  10
#define ID_  8
#define ED_  10
#define H_   128
#define LH_  256
#define DH_  64
#define BT_  (B_*T_)          // 5840
#define NPROW_ (BT_*P_)       // 58400
#define NIROW_ (BT_*NI_)      // 46720

typedef unsigned long long u64;

// ---------------------------------------------------------------------------
// Node encoders: 4 rows per block (grid 26280 instead of 105120)
// ---------------------------------------------------------------------------
__global__ __launch_bounds__(512) void k_enc(
    const float* __restrict__ pf, const float* __restrict__ jf,
    const float* __restrict__ Wpe, const float* __restrict__ bpe,
    const float* __restrict__ Wie, const float* __restrict__ bie,
    float* __restrict__ hp, float* __restrict__ hi)
{
    const int sub = threadIdx.x >> 7;
    const int j   = threadIdx.x & 127;
    const int r   = blockIdx.x*4 + sub;
    __shared__ float xs[4][16];
    if (r < NPROW_) {
        if (j < PD_) xs[sub][j] = pf[(size_t)r*PD_ + j];
    } else {
        if (j < ID_) xs[sub][j] = jf[(size_t)(r - NPROW_)*ID_ + j];
    }
    __syncthreads();
    if (r < NPROW_) {
        float acc = bpe[j];
        #pragma unroll
        for (int k = 0; k < PD_; k++) acc += xs[sub][k]*Wpe[k*H_ + j];
        hp[(size_t)r*H_ + j] = fmaxf(acc, 0.f);
    } else {
        float acc = bie[j];
        #pragma unroll
        for (int k = 0; k < ID_; k++) acc += xs[sub][k]*Wie[k*H_ + j];
        hi[(size_t)(r - NPROW_)*H_ + j] = fmaxf(acc, 0.f);
    }
}

// ---------------------------------------------------------------------------
// Fused GNN layer: one block per (b,t). Everything in LDS, no global atomics.
// ---------------------------------------------------------------------------
__device__ __forceinline__ void edge_block(
    int bt, int tid, int NE,
    const float* __restrict__ ef,     // edge feats, row stride NE*ED_
    const int*   __restrict__ eidx,   // (2,NE)
    const float* __restrict__ Wenc, const float* __restrict__ benc,
    const float* __restrict__ Wbot,   // 128x128
    const float* __restrict__ sproj,  // LDS: hpp_s or hip_s
    float* __restrict__ agg_s,        // LDS: 10x128, pre-zeroed
    float* __restrict__ ee_s, float* __restrict__ w_s,
    float* __restrict__ xr_s, int* __restrict__ src_s, int* __restrict__ dst_s)
{
    for (int e = tid; e < NE; e += 512) { src_s[e] = eidx[e]; dst_s[e] = eidx[NE + e]; }
    __syncthreads();

    const int c0 = (tid & 31) * 4;    // 4 cols
    const int r0 = (tid >> 5) * 2;    // 2 rows

    for (int rt = 0; rt < NE; rt += 32) {
        const int RT = (NE - rt < 32) ? (NE - rt) : 32;
        // raw edge feature tile
        for (int i = tid; i < RT*ED_; i += 512)
            xr_s[i] = ef[(size_t)bt*NE*ED_ + rt*ED_ + i];
        __syncthreads();
        // edge encoder: eenc = relu(xr @ Wenc + benc)  -> ee_s[RT][128]
        for (int o = tid; o < RT*H_; o += 512) {
            const int e = o >> 7, cc = o & 127;
            float a = benc[cc];
            #pragma unroll
            for (int k = 0; k < ED_; k++) a += xr_s[e*ED_ + k]*Wenc[k*H_ + cc];
            ee_s[o] = fmaxf(a, 0.f);
        }
        __syncthreads();
        // GEMM: (RT x 128) @ (128 x 128), j-step-4 with vector a-reads
        float acc0[4] = {0.f,0.f,0.f,0.f};
        float acc1[4] = {0.f,0.f,0.f,0.f};
        for (int kc = 0; kc < 4; kc++) {
            for (int i = tid; i < 32*H_; i += 512) {
                const int kk = i >> 7, cc = i & 127;
                w_s[i] = Wbot[(kc*32 + kk)*H_ + cc];
            }
            __syncthreads();
            #pragma unroll
            for (int j = 0; j < 32; j += 4) {
                const float4 w0 = *(const float4*)&w_s[(j+0)*H_ + c0];
                const float4 w1 = *(const float4*)&w_s[(j+1)*H_ + c0];
                const float4 w2 = *(const float4*)&w_s[(j+2)*H_ + c0];
                const float4 w3 = *(const float4*)&w_s[(j+3)*H_ + c0];
                const float4 a0 = *(const float4*)&ee_s[(r0    )*H_ + kc*32 + j];
                const float4 a1 = *(const float4*)&ee_s[(r0 + 1)*H_ + kc*32 + j];
                acc0[0] += a0.x*w0.x + a0.y*w1.x + a0.z*w2.x + a0.w*w3.x;
                acc0[1] += a0.x*w0.y + a0.y*w1.y + a0.z*w2.y + a0.w*w3.y;
                acc0[2] += a0.x*w0.z + a0.y*w1.z + a0.z*w2.z + a0.w*w3.z;
                acc0[3] += a0.x*w0.w + a0.y*w1.w + a0.z*w2.w + a0.w*w3.w;
                acc1[0] += a1.x*w0.x + a1.y*w1.x + a1.z*w2.x + a1.w*w3.x;
                acc1[1] += a1.x*w0.y + a1.y*w1.y + a1.z*w2.y + a1.w*w3.y;
                acc1[2] += a1.x*w0.z + a1.y*w1.z + a1.z*w2.z + a1.w*w3.z;
                acc1[3] += a1.x*w0.w + a1.y*w1.w + a1.z*w2.w + a1.w*w3.w;
            }
            __syncthreads();
        }
        // epilogue: m = relu(acc + sproj[src]) written back in-place over ee_s
        #pragma unroll
        for (int i = 0; i < 2; i++) {
            const int r = r0 + i;
            if (r < RT) {
                const int sidx = src_s[rt + r];
                const float* hr = sproj + sidx*H_ + c0;
                const float* a = (i == 0) ? acc0 : acc1;
                float4 v;
                v.x = fmaxf(a[0] + hr[0], 0.f);
                v.y = fmaxf(a[1] + hr[1], 0.f);
                v.z = fmaxf(a[2] + hr[2], 0.f);
                v.w = fmaxf(a[3] + hr[3], 0.f);
                *(float4*)&ee_s[r*H_ + c0] = v;
            }
        }
        __syncthreads();
        // aggregate into agg_s via LDS atomics
        {
            const int cc = tid & 127, gg = tid >> 7;
            for (int e = gg; e < RT; e += 4)
                atomicAdd(&agg_s[dst_s[rt + e]*H_ + cc], ee_s[e*H_ + cc]);
        }
        __syncthreads();
    }
}

__global__ __launch_bounds__(512) void k_layer(
    int l,
    const float* __restrict__ hp_in, const float* __restrict__ hi_g,
    const int* __restrict__ ip2p, const int* __restrict__ ii2p,
    const float* __restrict__ epf, const float* __restrict__ eif,
    const float* __restrict__ Wep, const float* __restrict__ bep,
    const float* __restrict__ Wei, const float* __restrict__ bei,
    const float* __restrict__ Wmp, const float* __restrict__ bmp,
    const float* __restrict__ Wmi, const float* __restrict__ bmi,
    const float* __restrict__ Wu,  const float* __restrict__ bu,
    float* __restrict__ hp_out)
{
    const int bt  = blockIdx.x;
    const int tid = threadIdx.x;

    __shared__ float hp_s [P_*H_];   // 1280
    __shared__ float hi_s [NI_*H_];  // 1024
    __shared__ float hpp_s[P_*H_];
    __shared__ float hip_s[NI_*H_];
    __shared__ float ee_s [32*H_];   // 4096 (edge tile / scratch)
    __shared__ float w_s  [32*H_];   // 4096 (W chunk / scratch)
    __shared__ float aggp_s[P_*H_];
    __shared__ float aggi_s[P_*H_];
    __shared__ float xr_s[32*ED_];
    __shared__ int   src_s[EP_], dst_s[EP_];

    // P0: load node states, zero aggregators
    for (int i = tid; i < P_*H_;  i += 512) hp_s[i] = hp_in[(size_t)bt*(P_*H_) + i];
    for (int i = tid; i < NI_*H_; i += 512) hi_s[i] = hi_g[(size_t)bt*(NI_*H_) + i];
    for (int i = tid; i < P_*H_;  i += 512) { aggp_s[i] = 0.f; aggi_s[i] = 0.f; }
    __syncthreads();

    const int c = tid & 127;
    const int g = tid >> 7;   // 0..3 (k-quarter)

    // P1: hpp = hp @ Wmp_top + bmp   (K=128 split over 4 groups)
    {
        const float* Wt = Wmp + (size_t)l*(2*H_*H_);
        float acc[P_];
        #pragma unroll
        for (int p = 0; p < P_; p++) acc[p] = 0.f;
        for (int j = 0; j < 32; j++) {
            const int k = g*32 + j;
            const float wv = Wt[k*H_ + c];
            #pragma unroll
            for (int p = 0; p < P_; p++) acc[p] += hp_s[p*H_ + k]*wv;
        }
        float* buf = (g < 2) ? (ee_s + g*(P_*H_)) : (w_s + (g - 2)*(P_*H_));
        #pragma unroll
        for (int p = 0; p < P_; p++) buf[p*H_ + c] = acc[p];
        __syncthreads();
        for (int o = tid; o < P_*H_; o += 512) {
            const int pp = o >> 7, cc = o & 127;
            hpp_s[o] = bmp[l*H_ + cc]
                     + ee_s[pp*H_ + cc] + ee_s[(P_ + pp)*H_ + cc]
                     + w_s [pp*H_ + cc] + w_s [(P_ + pp)*H_ + cc];
        }
        __syncthreads();
    }
    // P2: hip = hi @ Wmi_top + bmi
    {
        const float* Wt = Wmi + (size_t)l*(2*H_*H_);
        float acc[NI_];
        #pragma unroll
        for (int p = 0; p < NI_; p++) acc[p] = 0.f;
        for (int j = 0; j < 32; j++) {
            const int k = g*32 + j;
            const float wv = Wt[k*H_ + c];
            #pragma unroll
            for (int p = 0; p < NI_; p++) acc[p] += hi_s[p*H_ + k]*wv;
        }
        float* buf = ee_s + g*(NI_*H_);
        #pragma unroll
        for (int p = 0; p < NI_; p++) buf[p*H_ + c] = acc[p];
        __syncthreads();
        for (int o = tid; o < NI_*H_; o += 512) {
            const int pp = o >> 7, cc = o & 127;
            hip_s[o] = bmi[l*H_ + cc]
                     + ee_s[pp*H_ + cc]         + ee_s[1024 + pp*H_ + cc]
                     + ee_s[2048 + pp*H_ + cc]  + ee_s[3072 + pp*H_ + cc];
        }
        __syncthreads();
    }

    // P3-5: p2p edges -> aggp_s ; P6-8: i2p edges -> aggi_s
    edge_block(bt, tid, EP_, epf, ip2p, Wep, bep,
               Wmp + (size_t)l*(2*H_*H_) + H_*H_, hpp_s, aggp_s,
               ee_s, w_s, xr_s, src_s, dst_s);
    edge_block(bt, tid, EI_, eif, ii2p, Wei, bei,
               Wmi + (size_t)l*(2*H_*H_) + H_*H_, hip_s, aggi_s,
               ee_s, w_s, xr_s, src_s, dst_s);

    // P9: update h_p = relu([hp|aggp|aggi] @ Wu + bu)  (K=384 over 4 groups)
    {
        const float* Wl = Wu + (size_t)l*(3*H_*H_);
        float acc[P_];
        #pragma unroll
        for (int p = 0; p < P_; p++) acc[p] = 0.f;
        #pragma unroll
        for (int seg = 0; seg < 3; seg++) {
            const float* As = (seg == 0) ? hp_s : ((seg == 1) ? aggp_s : aggi_s);
            const int klo0 = seg*H_       > g*96       ? seg*H_       : g*96;
            const int khi0 = seg*H_ + H_  < g*96 + 96  ? seg*H_ + H_  : g*96 + 96;
            for (int k = klo0; k < khi0; k++) {
                const float wv = Wl[k*H_ + c];
                #pragma unroll
                for (int p = 0; p < P_; p++) acc[p] += As[p*H_ + (k - seg*H_)]*wv;
            }
        }
        float* buf = (g < 2) ? (ee_s + g*(P_*H_)) : (w_s + (g - 2)*(P_*H_));
        #pragma unroll
        for (int p = 0; p < P_; p++) buf[p*H_ + c] = acc[p];
        __syncthreads();
        for (int o = tid; o < P_*H_; o += 512) {
            const int pp = o >> 7, cc = o & 127;
            const float v = bu[l*H_ + cc]
                          + ee_s[pp*H_ + cc] + ee_s[(P_ + pp)*H_ + cc]
                          + w_s [pp*H_ + cc] + w_s [(P_ + pp)*H_ + cc];
            hp_out[(size_t)bt*(P_*H_) + o] = fmaxf(v, 0.f);
        }
    }
}

// ---------------------------------------------------------------------------
// xproj0 = emb @ Wx0 + lb0   (5840 x 1280 x 1024), tiled fp32 GEMM
// ---------------------------------------------------------------------------
__global__ __launch_bounds__(256) void k_gemm_xp(
    const float* __restrict__ A, const float* __restrict__ W,
    const float* __restrict__ bias, float* __restrict__ C)
{
    const int m0 = blockIdx.x*32;
    const int n0 = blockIdx.y*128;
    const int tid = threadIdx.x;
    __shared__ float As[32*32];
    __shared__ float Ws[32*128];
    const int c0 = (tid & 31)*4;
    const int r0 = (tid >> 5)*4;
    float acc[4][4] = {};
    for (int kc = 0; kc < 1280; kc += 32) {
        for (int i = tid; i < 1024; i += 256) {
            const int r = i >> 5, k = i & 31, row = m0 + r;
            As[i] = (row < BT_) ? A[(size_t)row*1280 + kc + k] : 0.f;
        }
        for (int i = tid; i < 4096; i += 256) {
            const int kk = i >> 7, cc = i & 127;
            Ws[i] = W[(size_t)(kc + kk)*1024 + n0 + cc];
        }
        __syncthreads();
        #pragma unroll 8
        for (int j = 0; j < 32; j++) {
            const float4 wv = *(const float4*)&Ws[j*128 + c0];
            const float a0 = As[(r0    )*32 + j];
            const float a1 = As[(r0 + 1)*32 + j];
            const float a2 = As[(r0 + 2)*32 + j];
            const float a3 = As[(r0 + 3)*32 + j];
            acc[0][0]+=a0*wv.x; acc[0][1]+=a0*wv.y; acc[0][2]+=a0*wv.z; acc[0][3]+=a0*wv.w;
            acc[1][0]+=a1*wv.x; acc[1][1]+=a1*wv.y; acc[1][2]+=a1*wv.z; acc[1][3]+=a1*wv.w;
            acc[2][0]+=a2*wv.x; acc[2][1]+=a2*wv.y; acc[2][2]+=a2*wv.z; acc[2][3]+=a2*wv.w;
            acc[3][0]+=a3*wv.x; acc[3][1]+=a3*wv.y; acc[3][2]+=a3*wv.z; acc[3][3]+=a3*wv.w;
        }
        __syncthreads();
    }
    #pragma unroll
    for (int i = 0; i < 4; i++) {
        const int row = m0 + r0 + i;
        if (row < BT_) {
            float4 o;
            o.x = acc[i][0] + bias[n0 + c0 + 0];
            o.y = acc[i][1] + bias[n0 + c0 + 1];
            o.z = acc[i][2] + bias[n0 + c0 + 2];
            o.w = acc[i][3] + bias[n0 + c0 + 3];
            *(float4*)&C[(size_t)row*1024 + n0 + c0] = o;
        }
    }
}

// ---------------------------------------------------------------------------
// Persistent 2-layer LSTM scan, FENCE-FREE.
// 64 WGs: 0-31 = layer0 slices, 32-63 = layer1. Each WG owns 8 h-cols
// (32 gate cols), Wh slice in registers. h exchanged via RELAXED AGENT-SCOPE
// ATOMICS (sc1 path, chip-coherent point) -> no threadfence L2 wb/inv.
// Producer ordering: data stores -> s_waitcnt vmcnt(0) -> flag store.
// Exchange buffers are history-indexed (write-once) -> no WAR hazards.
// ---------------------------------------------------------------------------
__device__ __forceinline__ float sigm(float x) { return 1.f/(1.f + expf(-x)); }

__global__ __launch_bounds__(512) void k_lstm_scan(
    const float* __restrict__ xproj0,                    // [5840][1024] (lb0 folded)
    const float* __restrict__ Wh0,
    const float* __restrict__ Wx1, const float* __restrict__ Wh1,
    const float* __restrict__ lb1,
    float* __restrict__ h1_ex, float* __restrict__ h2_ex, // [366][256][16]
    float* __restrict__ h2_out,                           // [5840][256]
    int* __restrict__ flag0, int* __restrict__ flag1)
{
    const int tid   = threadIdx.x;
    const int layer = blockIdx.x >> 5;
    const int s     = blockIdx.x & 31;
    const int cc    = tid & 31;          // local gate col 0..31  (q = cc>>3, j = cc&7)
    const int g     = tid >> 5;          // k-group 0..15; == batch index in z phase
    const int gcol  = (cc >> 3)*256 + s*8 + (cc & 7);

    __shared__ float h_s[8192];          // staged h ([k][b]); layer0 uses 4096
    __shared__ float red[16*544];        // partial sums, stride-17 pad (conflict-free)
    __shared__ float z_s[16*33];         // z[b][gatecol], pad 33

    float w[32];
    if (layer == 0) {
        #pragma unroll
        for (int j = 0; j < 16; j++) w[j] = Wh0[(size_t)(g*16 + j)*1024 + gcol];
    } else {
        #pragma unroll
        for (int j = 0; j < 32; j++) {
            const int k = g*32 + j;
            w[j] = (k < 256) ? Wx1[(size_t)k*1024 + gcol]
                             : Wh1[(size_t)(k - 256)*1024 + gcol];
        }
    }

    // writer mapping (tid < 64, i.e. wave 0): h-col wj, batches wb, wb+1
    const int wj = tid >> 3, wb = (tid & 7)*2;
    float cst0 = 0.f, cst1 = 0.f;
    const float xv_l1 = lb1[gcol];

    const u64* ex1 = (const u64*)h1_ex;
    const u64* ex2 = (const u64*)h2_ex;

    for (int t = 0; t < T_; t++) {
        // x contribution prefetch (independent of flags)
        float xv;
        if (layer == 0) xv = xproj0[((size_t)g*T_ + t)*1024 + gcol];
        else            xv = xv_l1;

        // wait for producers (skip own flag: we set it ourselves)
        if (layer == 0) {
            if (tid < 32 && tid != s)
                while (__hip_atomic_load(&flag0[tid], __ATOMIC_RELAXED, __HIP_MEMORY_SCOPE_AGENT) < t) {}
        } else {
            if (tid < 32) {
                while (__hip_atomic_load(&flag0[tid], __ATOMIC_RELAXED, __HIP_MEMORY_SCOPE_AGENT) < t + 1) {}
            } else if (tid < 64 && (tid - 32) != s) {
                while (__hip_atomic_load(&flag1[tid - 32], __ATOMIC_RELAXED, __HIP_MEMORY_SCOPE_AGENT) < t) {}
            }
        }
        __syncthreads();                                      // S1

        // stage h into LDS via coherent u64 loads
        if (layer == 0) {
            #pragma unroll
            for (int i = 0; i < 4; i++) {
                const int idx = tid + i*512;
                u64 v = __hip_atomic_load(&ex1[(size_t)t*2048 + idx], __ATOMIC_RELAXED, __HIP_MEMORY_SCOPE_AGENT);
                *(u64*)&h_s[2*idx] = v;
            }
        } else {
            #pragma unroll
            for (int i = 0; i < 4; i++) {
                const int idx = tid + i*512;
                u64 v1 = __hip_atomic_load(&ex1[(size_t)(t + 1)*2048 + idx], __ATOMIC_RELAXED, __HIP_MEMORY_SCOPE_AGENT);
                u64 v2 = __hip_atomic_load(&ex2[(size_t)t*2048 + idx],       __ATOMIC_RELAXED, __HIP_MEMORY_SCOPE_AGENT);
                *(u64*)&h_s[2*idx]        = v1;
                *(u64*)&h_s[4096 + 2*idx] = v2;
            }
        }
        __syncthreads();                                      // S2

        // gate GEMM: acc[b] = sum_j w[j] * h[k(j)][b]
        float acc[16];
        #pragma unroll
        for (int i = 0; i < 16; i++) acc[i] = 0.f;
        if (layer == 0) {
            #pragma unroll
            for (int j = 0; j < 16; j++) {
                const float wv = w[j];
                const float4* hp4 = (const float4*)&h_s[(g*16 + j)*16];
                const float4 h0 = hp4[0], h1v = hp4[1], h2v = hp4[2], h3v = hp4[3];
                acc[0]+=h0.x*wv;  acc[1]+=h0.y*wv;  acc[2]+=h0.z*wv;  acc[3]+=h0.w*wv;
                acc[4]+=h1v.x*wv; acc[5]+=h1v.y*wv; acc[6]+=h1v.z*wv; acc[7]+=h1v.w*wv;
                acc[8]+=h2v.x*wv; acc[9]+=h2v.y*wv; acc[10]+=h2v.z*wv;acc[11]+=h2v.w*wv;
                acc[12]+=h3v.x*wv;acc[13]+=h3v.y*wv;acc[14]+=h3v.z*wv;acc[15]+=h3v.w*wv;
            }
        } else {
            #pragma unroll
            for (int j = 0; j < 32; j++) {
                const float wv = w[j];
                const float4* hp4 = (const float4*)&h_s[(g*32 + j)*16];
                const float4 h0 = hp4[0], h1v = hp4[1], h2v = hp4[2], h3v = hp4[3];
                acc[0]+=h0.x*wv;  acc[1]+=h0.y*wv;  acc[2]+=h0.z*wv;  acc[3]+=h0.w*wv;
                acc[4]+=h1v.x*wv; acc[5]+=h1v.y*wv; acc[6]+=h1v.z*wv; acc[7]+=h1v.w*wv;
                acc[8]+=h2v.x*wv; acc[9]+=h2v.y*wv; acc[10]+=h2v.z*wv;acc[11]+=h2v.w*wv;
                acc[12]+=h3v.x*wv;acc[13]+=h3v.y*wv;acc[14]+=h3v.z*wv;acc[15]+=h3v.w*wv;
            }
        }
        // partials -> LDS, stride-17 (conflict-free both sides)
        {
            float* rp = &red[g*544 + cc*17];
            #pragma unroll
            for (int b = 0; b < 16; b++) rp[b] = acc[b];
        }
        __syncthreads();                                      // S3

        // z = xv + sum over 16 k-groups; thread handles (col=cc, batch=g)
        {
            float zsum = xv;
            #pragma unroll
            for (int g2 = 0; g2 < 16; g2++) zsum += red[g2*544 + cc*17 + g];
            z_s[g*33 + cc] = zsum;
        }
        __syncthreads();                                      // S4

        // cell update: wave 0 only; each thread owns (h-col wj, batches wb,wb+1)
        if (tid < 64) {
            const float zi0 = z_s[wb*33      + wj      ];
            const float zf0 = z_s[wb*33      + 8  + wj ];
            const float zg0 = z_s[wb*33      + 16 + wj ];
            const float zo0 = z_s[wb*33      + 24 + wj ];
            const float zi1 = z_s[(wb+1)*33  + wj      ];
            const float zf1 = z_s[(wb+1)*33  + 8  + wj ];
            const float zg1 = z_s[(wb+1)*33  + 16 + wj ];
            const float zo1 = z_s[(wb+1)*33  + 24 + wj ];
            cst0 = sigm(zf0)*cst0 + sigm(zi0)*tanhf(zg0);
            const float h0 = sigm(zo0)*tanhf(cst0);
            cst1 = sigm(zf1)*cst1 + sigm(zi1)*tanhf(zg1);
            const float h1o = sigm(zo1)*tanhf(cst1);
            union { float f[2]; u64 u; } pk;
            pk.f[0] = h0; pk.f[1] = h1o;
            u64* dst = (u64*)((layer == 0 ? h1_ex : h2_ex)
                              + (size_t)(t + 1)*4096 + (s*8 + wj)*16 + wb);
            __hip_atomic_store(dst, pk.u, __ATOMIC_RELAXED, __HIP_MEMORY_SCOPE_AGENT);
            if (layer == 1) {
                h2_out[((size_t)wb*T_     + t)*LH_ + s*8 + wj] = h0;
                h2_out[((size_t)(wb+1)*T_ + t)*LH_ + s*8 + wj] = h1o;
            }
        }
        // drain data stores to the coherent point, then publish
        asm volatile("s_waitcnt vmcnt(0)" ::: "memory");
        if (tid == 0) {
            int* f = (layer == 0) ? &flag0[s] : &flag1[s];
            __hip_atomic_store(f, t + 1, __ATOMIC_RELAXED, __HIP_MEMORY_SCOPE_AGENT);
        }
    }
}

// ---------------------------------------------------------------------------
// Decoder MLP + softplus, 4 rows per block (grid 1460)
// ---------------------------------------------------------------------------
__global__ __launch_bounds__(256) void k_dec(
    const float* __restrict__ h2,
    const float* __restrict__ Wd1, const float* __restrict__ bd1, const float* __restrict__ a1p,
    const float* __restrict__ Wd2, const float* __restrict__ bd2, const float* __restrict__ a2p,
    const float* __restrict__ Wd3, const float* __restrict__ bd3,
    float* __restrict__ oil, float* __restrict__ water)
{
    const int sub = threadIdx.x >> 6;
    const int tid = threadIdx.x & 63;
    const int r   = blockIdx.x*4 + sub;    // BT_ % 4 == 0, always valid
    __shared__ float hrow[4][256], d1s[4][64], d2s[4][64];
    for (int i = tid; i < 256; i += 64) hrow[sub][i] = h2[(size_t)r*256 + i];
    __syncthreads();
    const float a1 = a1p[0], a2 = a2p[0];
    float acc = bd1[tid];
    for (int k = 0; k < 256; k++) acc += hrow[sub][k]*Wd1[k*64 + tid];
    d1s[sub][tid] = (acc >= 0.f) ? acc : a1*acc;
    __syncthreads();
    acc = bd2[tid];
    for (int k = 0; k < 64; k++) acc += d1s[sub][k]*Wd2[k*64 + tid];
    d2s[sub][tid] = (acc >= 0.f) ? acc : a2*acc;
    __syncthreads();
    if (tid < 20) {
        acc = bd3[tid];
        for (int k = 0; k < 64; k++) acc += d2s[sub][k]*Wd3[k*20 + tid];
        const float spv = (acc > 20.f) ? acc : log1pf(expf(acc));
        const int p = tid >> 1;
        if (tid & 1) water[(size_t)r*10 + p] = spv;
        else         oil  [(size_t)r*10 + p] = spv;
    }
}

// ---------------------------------------------------------------------------
extern "C" void kernel_launch(void* const* d_in, const int* in_sizes, int n_in,
                              void* d_out, int out_size, void* d_ws, size_t ws_size,
                              hipStream_t stream)
{
    const float* pf  = (const float*)d_in[0];
    const float* jf  = (const float*)d_in[1];
    const float* epf = (const float*)d_in[2];
    const float* eif = (const float*)d_in[3];
    const int*   ip2p= (const int*)d_in[4];
    const int*   ii2p= (const int*)d_in[5];
    const float* Wpe = (const float*)d_in[6];  const float* bpe = (const float*)d_in[7];
    const float* Wie = (const float*)d_in[8];  const float* bie = (const float*)d_in[9];
    const float* Wep = (const float*)d_in[10]; const float* bep = (const float*)d_in[11];
    const float* Wei = (const float*)d_in[12]; const float* bei = (const float*)d_in[13];
    const float* Wmp = (const float*)d_in[14]; const float* bmp = (const float*)d_in[15];
    const float* Wmi = (const float*)d_in[16]; const float* bmi = (const float*)d_in[17];
    const float* Wu  = (const float*)d_in[18]; const float* bu  = (const float*)d_in[19];
    const float* Wx0 = (const float*)d_in[20]; const float* Wh0 = (const float*)d_in[21];
    const float* lb0 = (const float*)d_in[22];
    const float* Wx1 = (const float*)d_in[23]; const float* Wh1 = (const float*)d_in[24];
    const float* lb1 = (const float*)d_in[25];
    const float* Wd1 = (const float*)d_in[26]; const float* bd1 = (const float*)d_in[27];
    const float* a1  = (const float*)d_in[28];
    const float* Wd2 = (const float*)d_in[29]; const float* bd2 = (const float*)d_in[30];
    const float* a2  = (const float*)d_in[31];
    const float* Wd3 = (const float*)d_in[32]; const float* bd3 = (const float*)d_in[33];

    float* oil   = (float*)d_out;
    float* water = oil + NPROW_;
    float* emb   = water + NPROW_;          // (B,T,P,H) fp32, also LSTM input

    float* ws    = (float*)d_ws;
    float* X0    = ws;                       // 7,475,200
    float* X1    = X0 + 7475200;             // 7,475,200
    float* hibuf = X1 + 7475200;             // 5,980,160
    float* xp0   = hibuf + 5980160;          // 5,980,160
    float* h1ex  = xp0 + 5980160;            // 1,499,136 (366*256*16)
    float* h2ex  = h1ex + 1499136;           // 1,499,136
    float* h2o   = h2ex + 1499136;           // 1,495,040
    int*   flag0 = (int*)(h2o + 1495040);
    int*   flag1 = flag0 + 32;

    hipMemsetAsync(flag0, 0, 64*sizeof(int), stream);
    hipMemsetAsync(h1ex, 0, 4096*sizeof(float), stream);   // h1[-1] = 0
    hipMemsetAsync(h2ex, 0, 4096*sizeof(float), stream);   // h2[-1] = 0

    k_enc<<<(NPROW_ + NIROW_)/4, 512, 0, stream>>>(pf, jf, Wpe, bpe, Wie, bie, X0, hibuf);

    k_layer<<<BT_, 512, 0, stream>>>(0, X0, hibuf, ip2p, ii2p, epf, eif,
        Wep, bep, Wei, bei, Wmp, bmp, Wmi, bmi, Wu, bu, X1);
    k_layer<<<BT_, 512, 0, stream>>>(1, X1, hibuf, ip2p, ii2p, epf, eif,
        Wep, bep, Wei, bei, Wmp, bmp, Wmi, bmi, Wu, bu, X0);
    k_layer<<<BT_, 512, 0, stream>>>(2, X0, hibuf, ip2p, ii2p, epf, eif,
        Wep, bep, Wei, bei, Wmp, bmp, Wmi, bmi, Wu, bu, emb);

    dim3 gx((BT_ + 31)/32, 8);
    k_gemm_xp<<<gx, 256, 0, stream>>>(emb, Wx0, lb0, xp0);

    k_lstm_scan<<<64, 512, 0, stream>>>(xp0, Wh0, Wx1, Wh1, lb1,
                                        h1ex, h2ex, h2o, flag0, flag1);

    k_dec<<<BT_/4, 256, 0, stream>>>(h2o, Wd1, bd1, a1, Wd2, bd2, a2, Wd3, bd3, oil, water);
}

// Round 4
// 5068.190 us; speedup vs baseline: 2.4571x; 1.9116x over previous
//
#include <hip/hip_runtime.h>

#define B_   16
#define T_   365
#define P_   10
#define NI_  8
#define EP_  90
#define EI_  80
#define PD_  10
#define ID_  8
#define ED_  10
#define H_   128
#define LH_  256
#define DH_  64
#define BT_  (B_*T_)          // 5840
#define NPROW_ (BT_*P_)       // 58400
#define NIROW_ (BT_*NI_)      // 46720

typedef unsigned long long u64;
typedef __attribute__((ext_vector_type(8))) short short8b;   // 8 bf16 (4 VGPRs)
typedef __attribute__((ext_vector_type(4))) float f32x4;     // MFMA C/D

#define MFMA_BF16(a,b,c) __builtin_amdgcn_mfma_f32_16x16x32_bf16(a,b,c,0,0,0)

// fp32 -> bf16 with round-to-nearest-even
__device__ __forceinline__ short f2bf(float f){
    union { float f; unsigned u; } a; a.f = f;
    unsigned r = a.u + 0x7fffu + ((a.u >> 16) & 1u);
    return (short)(r >> 16);
}

// swizzled LDS A-tile addressing: row-major bf16, rowstrideB bytes/row,
// 16B slot index XORed with (row&7) -> 2-way conflict (free) on frag reads
__device__ __forceinline__ short* lds_a(short* base, int row, int kbyte, int rowstrideB){
    return (short*)((char*)base + row*rowstrideB + (kbyte ^ ((row & 7) << 4)));
}
__device__ __forceinline__ void st_bf(short* base, int row, int col, int rowstrideB, short v){
    *(short*)((char*)base + row*rowstrideB + ((2*col) ^ ((row & 7) << 4))) = v;
}

// ---------------------------------------------------------------------------
// Weight prep: transpose + convert to bf16, [N][K] layout (B-fragment friendly)
// wbf layout (shorts): WencPT[128][32] @0, WencIT @4096,
//   WtopPT 3x[128][128] @8192, WtopIT @57344, WbotPT @106496, WbotIT @155648,
//   WuT 3x[128][384] @204800. total 352256 shorts.
// ---------------------------------------------------------------------------
#define WBF_TOTAL 352256
__global__ __launch_bounds__(512) void k_prep(
    const float* __restrict__ Wep, const float* __restrict__ Wei,
    const float* __restrict__ Wmp, const float* __restrict__ Wmi,
    const float* __restrict__ Wu,  short* __restrict__ wbf)
{
    int i = blockIdx.x*512 + threadIdx.x;
    if (i >= WBF_TOTAL) return;
    short v;
    if (i < 8192) {                          // encoders, K padded 10->32 with zeros
        const float* W = (i < 4096) ? Wep : Wei;
        int j = i & 4095, c = j >> 5, k = j & 31;
        v = (k < PD_) ? f2bf(W[k*H_ + c]) : (short)0;
    } else if (i < 106496) {                 // top halves of Wmp/Wmi
        int j = i - 8192;
        const float* W = (j < 49152) ? Wmp : Wmi;
        j %= 49152;
        int l = j >> 14, r = j & 16383, c = r >> 7, k = r & 127;
        v = f2bf(W[l*2*H_*H_ + k*H_ + c]);
    } else if (i < 204800) {                 // bottom halves
        int j = i - 106496;
        const float* W = (j < 49152) ? Wmp : Wmi;
        j %= 49152;
        int l = j >> 14, r = j & 16383, c = r >> 7, k = r & 127;
        v = f2bf(W[l*2*H_*H_ + (H_ + k)*H_ + c]);
    } else {                                 // Wu: [384][128] -> [128][384]
        int j = i - 204800;
        int l = j / 49152, r = j % 49152, c = r / 384, k = r % 384;
        v = f2bf(Wu[l*3*H_*H_ + k*H_ + c]);
    }
    wbf[i] = v;
}

// ---------------------------------------------------------------------------
// Node encoders: 4 rows per block
// ---------------------------------------------------------------------------
__global__ __launch_bounds__(512) void k_enc(
    const float* __restrict__ pf, const float* __restrict__ jf,
    const float* __restrict__ Wpe, const float* __restrict__ bpe,
    const float* __restrict__ Wie, const float* __restrict__ bie,
    float* __restrict__ hp, float* __restrict__ hi)
{
    const int sub = threadIdx.x >> 7;
    const int j   = threadIdx.x & 127;
    const int r   = blockIdx.x*4 + sub;
    __shared__ float xs[4][16];
    if (r < NPROW_) {
        if (j < PD_) xs[sub][j] = pf[(size_t)r*PD_ + j];
    } else {
        if (j < ID_) xs[sub][j] = jf[(size_t)(r - NPROW_)*ID_ + j];
    }
    __syncthreads();
    if (r < NPROW_) {
        float acc = bpe[j];
        #pragma unroll
        for (int k = 0; k < PD_; k++) acc += xs[sub][k]*Wpe[k*H_ + j];
        hp[(size_t)r*H_ + j] = fmaxf(acc, 0.f);
    } else {
        float acc = bie[j];
        #pragma unroll
        for (int k = 0; k < ID_; k++) acc += xs[sub][k]*Wie[k*H_ + j];
        hi[(size_t)(r - NPROW_)*H_ + j] = fmaxf(acc, 0.f);
    }
}

// ---------------------------------------------------------------------------
// Fused GNN layer, MFMA bf16. One block (512 thr, 8 waves) per (b,t).
// Wave wv owns output col-tile [16*wv, 16*wv+16). B-frags read from global
// (prepped bf16 [N][K], L2-resident). A-tiles in swizzled LDS bf16.
// ---------------------------------------------------------------------------
__device__ __forceinline__ void edge_phase(
    int bt, int tid, int wv, int ln15, int lg, int NE,
    const float* __restrict__ ef, const int* __restrict__ eidx,
    const short* __restrict__ WencT, const float* __restrict__ benc,
    const short* __restrict__ WbotT,
    const float* __restrict__ hproj_s, float* __restrict__ agg_s,
    short* __restrict__ eenc_A, short* __restrict__ raw_A,
    int* __restrict__ src_s, int* __restrict__ dst_s)
{
    for (int e = tid; e < NE; e += 512) { src_s[e] = eidx[e]; dst_s[e] = eidx[NE + e]; }

    const int c = 16*wv + ln15;
    const float bv = benc[c];

    for (int tb = 0; tb < NE; tb += 32) {
        const int RT = (NE - tb < 32) ? (NE - tb) : 32;
        __syncthreads();                         // prior tile reads done / src ready
        // zero raw_A (32 rows x 64 shorts, 128B stride) = 1024 u32
        ((unsigned*)raw_A)[tid] = 0u;
        ((unsigned*)raw_A)[tid + 512] = 0u;
        __syncthreads();
        // fill raw edge features (bf16, swizzled)
        for (int i = tid; i < RT*ED_; i += 512) {
            const int e = i/ED_, k = i - e*ED_;
            st_bf(raw_A, e, k, 128, f2bf(ef[(size_t)bt*NE*ED_ + (tb + e)*ED_ + k]));
        }
        __syncthreads();
        // edge encoder: eenc = relu(raw @ Wenc + benc), K=32 (zero-padded)
        #pragma unroll
        for (int rtl = 0; rtl < 2; rtl++) {
            short8b a = *(short8b*)lds_a(raw_A, 16*rtl + ln15, lg*16, 128);
            short8b b = *(const short8b*)&WencT[(size_t)c*32 + lg*8];
            f32x4 acc = {0.f,0.f,0.f,0.f};
            acc = MFMA_BF16(a, b, acc);
            #pragma unroll
            for (int j = 0; j < 4; j++) {
                const int row = 16*rtl + lg*4 + j;
                st_bf(eenc_A, row, c, 256, f2bf(fmaxf(acc[j] + bv, 0.f)));
            }
        }
        __syncthreads();
        // message GEMM: (32 x 128) @ (128 x 128)
        f32x4 acc0 = {0.f,0.f,0.f,0.f}, acc1 = {0.f,0.f,0.f,0.f};
        #pragma unroll
        for (int kc = 0; kc < 4; kc++) {
            short8b b  = *(const short8b*)&WbotT[(size_t)c*128 + kc*32 + lg*8];
            short8b a0 = *(short8b*)lds_a(eenc_A, ln15,      kc*64 + lg*16, 256);
            short8b a1 = *(short8b*)lds_a(eenc_A, 16 + ln15, kc*64 + lg*16, 256);
            acc0 = MFMA_BF16(a0, b, acc0);
            acc1 = MFMA_BF16(a1, b, acc1);
        }
        // epilogue: m = relu(acc + hproj[src]); scatter-add to agg
        #pragma unroll
        for (int j = 0; j < 4; j++) {
            const int el0 = lg*4 + j;
            if (el0 < RT) {
                const int e = tb + el0;
                const float m = fmaxf(acc0[j] + hproj_s[src_s[e]*H_ + c], 0.f);
                atomicAdd(&agg_s[dst_s[e]*H_ + c], m);
            }
            const int el1 = 16 + lg*4 + j;
            if (el1 < RT) {
                const int e = tb + el1;
                const float m = fmaxf(acc1[j] + hproj_s[src_s[e]*H_ + c], 0.f);
                atomicAdd(&agg_s[dst_s[e]*H_ + c], m);
            }
        }
    }
}

__global__ __launch_bounds__(512) void k_layer(
    int l,
    const float* __restrict__ hp_in, const float* __restrict__ hi_g,
    const int* __restrict__ ip2p, const int* __restrict__ ii2p,
    const float* __restrict__ epf, const float* __restrict__ eif,
    const short* __restrict__ wbf,
    const float* __restrict__ bep, const float* __restrict__ bei,
    const float* __restrict__ bmp, const float* __restrict__ bmi,
    const float* __restrict__ bu,
    float* __restrict__ hp_out)
{
    const int bt   = blockIdx.x;
    const int tid  = threadIdx.x;
    const int wv   = tid >> 6;
    const int lane = tid & 63;
    const int ln15 = lane & 15;
    const int lg   = lane >> 4;

    __shared__ short h_s[32*128];      // rows 0-15: hp (10 real), 16-31: hi (8 real)
    __shared__ float hpp_s[P_*H_];
    __shared__ float hip_s[NI_*H_];
    __shared__ float aggp_s[P_*H_];
    __shared__ float aggi_s[P_*H_];
    __shared__ short eenc_A[32*128];
    __shared__ short updA[16*384];     // first 4096B alias raw_A
    __shared__ int   src_s[EP_], dst_s[EP_];
    short* raw_A = updA;

    const short* WencPT = wbf;
    const short* WencIT = wbf + 4096;
    const short* WtopPT = wbf + 8192   + l*16384;
    const short* WtopIT = wbf + 57344  + l*16384;
    const short* WbotPT = wbf + 106496 + l*16384;
    const short* WbotIT = wbf + 155648 + l*16384;
    const short* WuT    = wbf + 204800 + l*49152;
    const float* bmp_g = bmp + l*H_;
    const float* bmi_g = bmi + l*H_;
    const float* bu_g  = bu  + l*H_;

    // stage h -> bf16 LDS (swizzled), zero aggregators
    for (int i = tid; i < P_*H_; i += 512) {
        const int r = i >> 7, c = i & 127;
        st_bf(h_s, r, c, 256, f2bf(hp_in[(size_t)bt*(P_*H_) + i]));
        aggp_s[i] = 0.f; aggi_s[i] = 0.f;
    }
    for (int i = tid; i < NI_*H_; i += 512) {
        const int r = i >> 7, c = i & 127;
        st_bf(h_s, 16 + r, c, 256, f2bf(hi_g[(size_t)bt*(NI_*H_) + i]));
    }
    __syncthreads();

    // hpp = hp @ WmpTop + bmp ; hip = hi @ WmiTop + bmi   (no relu)
    {
        f32x4 accp = {0.f,0.f,0.f,0.f}, acci = {0.f,0.f,0.f,0.f};
        const int c = 16*wv + ln15;
        #pragma unroll
        for (int kc = 0; kc < 4; kc++) {
            short8b ap = *(short8b*)lds_a(h_s, ln15,      kc*64 + lg*16, 256);
            short8b bp = *(const short8b*)&WtopPT[(size_t)c*128 + kc*32 + lg*8];
            accp = MFMA_BF16(ap, bp, accp);
            short8b ai = *(short8b*)lds_a(h_s, 16 + ln15, kc*64 + lg*16, 256);
            short8b bi = *(const short8b*)&WtopIT[(size_t)c*128 + kc*32 + lg*8];
            acci = MFMA_BF16(ai, bi, acci);
        }
        const float bpv = bmp_g[c], biv = bmi_g[c];
        #pragma unroll
        for (int j = 0; j < 4; j++) {
            const int r = lg*4 + j;
            if (r < P_)  hpp_s[r*H_ + c] = accp[j] + bpv;
            if (r < NI_) hip_s[r*H_ + c] = acci[j] + biv;
        }
    }
    __syncthreads();

    edge_phase(bt, tid, wv, ln15, lg, EP_, epf, ip2p, WencPT, bep, WbotPT,
               hpp_s, aggp_s, eenc_A, raw_A, src_s, dst_s);
    __syncthreads();
    edge_phase(bt, tid, wv, ln15, lg, EI_, eif, ii2p, WencIT, bei, WbotIT,
               hip_s, aggi_s, eenc_A, raw_A, src_s, dst_s);
    __syncthreads();

    // build update A = [hp | aggp | aggi] bf16, 16x384 (rows 10-15 garbage, unread)
    for (int i = tid; i < P_*H_; i += 512) {
        const int r = i >> 7, c = i & 127;
        const short hv = *(short*)((char*)h_s + r*256 + ((2*c) ^ ((r & 7) << 4)));
        st_bf(updA, r, c,        768, hv);
        st_bf(updA, r, 128 + c,  768, f2bf(aggp_s[i]));
        st_bf(updA, r, 256 + c,  768, f2bf(aggi_s[i]));
    }
    __syncthreads();

    // h_out = relu([hp|aggp|aggi] @ Wu + bu)
    {
        f32x4 acc = {0.f,0.f,0.f,0.f};
        const int c = 16*wv + ln15;
        #pragma unroll
        for (int kc = 0; kc < 12; kc++) {
            short8b a = *(short8b*)lds_a(updA, ln15, kc*64 + lg*16, 768);
            short8b b = *(const short8b*)&WuT[(size_t)c*384 + kc*32 + lg*8];
            acc = MFMA_BF16(a, b, acc);
        }
        const float bv = bu_g[c];
        #pragma unroll
        for (int j = 0; j < 4; j++) {
            const int r = lg*4 + j;
            if (r < P_)
                hp_out[(size_t)bt*(P_*H_) + r*H_ + c] = fmaxf(acc[j] + bv, 0.f);
        }
    }
}

// ---------------------------------------------------------------------------
// xproj0 = emb @ Wx0 + lb0   (5840 x 1280 x 1024), tiled fp32 GEMM
// ---------------------------------------------------------------------------
__global__ __launch_bounds__(256) void k_gemm_xp(
    const float* __restrict__ A, const float* __restrict__ W,
    const float* __restrict__ bias, float* __restrict__ C)
{
    const int m0 = blockIdx.x*32;
    const int n0 = blockIdx.y*128;
    const int tid = threadIdx.x;
    __shared__ float As[32*32];
    __shared__ float Ws[32*128];
    const int c0 = (tid & 31)*4;
    const int r0 = (tid >> 5)*4;
    float acc[4][4] = {};
    for (int kc = 0; kc < 1280; kc += 32) {
        for (int i = tid; i < 1024; i += 256) {
            const int r = i >> 5, k = i & 31, row = m0 + r;
            As[i] = (row < BT_) ? A[(size_t)row*1280 + kc + k] : 0.f;
        }
        for (int i = tid; i < 4096; i += 256) {
            const int kk = i >> 7, cc = i & 127;
            Ws[i] = W[(size_t)(kc + kk)*1024 + n0 + cc];
        }
        __syncthreads();
        #pragma unroll 8
        for (int j = 0; j < 32; j++) {
            const float4 wv = *(const float4*)&Ws[j*128 + c0];
            const float a0 = As[(r0    )*32 + j];
            const float a1 = As[(r0 + 1)*32 + j];
            const float a2 = As[(r0 + 2)*32 + j];
            const float a3 = As[(r0 + 3)*32 + j];
            acc[0][0]+=a0*wv.x; acc[0][1]+=a0*wv.y; acc[0][2]+=a0*wv.z; acc[0][3]+=a0*wv.w;
            acc[1][0]+=a1*wv.x; acc[1][1]+=a1*wv.y; acc[1][2]+=a1*wv.z; acc[1][3]+=a1*wv.w;
            acc[2][0]+=a2*wv.x; acc[2][1]+=a2*wv.y; acc[2][2]+=a2*wv.z; acc[2][3]+=a2*wv.w;
            acc[3][0]+=a3*wv.x; acc[3][1]+=a3*wv.y; acc[3][2]+=a3*wv.z; acc[3][3]+=a3*wv.w;
        }
        __syncthreads();
    }
    #pragma unroll
    for (int i = 0; i < 4; i++) {
        const int row = m0 + r0 + i;
        if (row < BT_) {
            float4 o;
            o.x = acc[i][0] + bias[n0 + c0 + 0];
            o.y = acc[i][1] + bias[n0 + c0 + 1];
            o.z = acc[i][2] + bias[n0 + c0 + 2];
            o.w = acc[i][3] + bias[n0 + c0 + 3];
            *(float4*)&C[(size_t)row*1024 + n0 + c0] = o;
        }
    }
}

// ---------------------------------------------------------------------------
// Persistent 2-layer LSTM scan, fence-free (relaxed agent-scope atomics)
// ---------------------------------------------------------------------------
__device__ __forceinline__ float sigm(float x) { return 1.f/(1.f + expf(-x)); }

__global__ __launch_bounds__(512) void k_lstm_scan(
    const float* __restrict__ xproj0,
    const float* __restrict__ Wh0,
    const float* __restrict__ Wx1, const float* __restrict__ Wh1,
    const float* __restrict__ lb1,
    float* __restrict__ h1_ex, float* __restrict__ h2_ex,
    float* __restrict__ h2_out,
    int* __restrict__ flag0, int* __restrict__ flag1)
{
    const int tid   = threadIdx.x;
    const int layer = blockIdx.x >> 5;
    const int s     = blockIdx.x & 31;
    const int cc    = tid & 31;
    const int g     = tid >> 5;
    const int gcol  = (cc >> 3)*256 + s*8 + (cc & 7);

    __shared__ float h_s[8192];
    __shared__ float red[16*544];
    __shared__ float z_s[16*33];

    float w[32];
    if (layer == 0) {
        #pragma unroll
        for (int j = 0; j < 16; j++) w[j] = Wh0[(size_t)(g*16 + j)*1024 + gcol];
    } else {
        #pragma unroll
        for (int j = 0; j < 32; j++) {
            const int k = g*32 + j;
            w[j] = (k < 256) ? Wx1[(size_t)k*1024 + gcol]
                             : Wh1[(size_t)(k - 256)*1024 + gcol];
        }
    }

    const int wj = tid >> 3, wb = (tid & 7)*2;
    float cst0 = 0.f, cst1 = 0.f;
    const float xv_l1 = lb1[gcol];

    const u64* ex1 = (const u64*)h1_ex;
    const u64* ex2 = (const u64*)h2_ex;

    for (int t = 0; t < T_; t++) {
        float xv;
        if (layer == 0) xv = xproj0[((size_t)g*T_ + t)*1024 + gcol];
        else            xv = xv_l1;

        if (layer == 0) {
            if (tid < 32 && tid != s)
                while (__hip_atomic_load(&flag0[tid], __ATOMIC_RELAXED, __HIP_MEMORY_SCOPE_AGENT) < t) {}
        } else {
            if (tid < 32) {
                while (__hip_atomic_load(&flag0[tid], __ATOMIC_RELAXED, __HIP_MEMORY_SCOPE_AGENT) < t + 1) {}
            } else if (tid < 64 && (tid - 32) != s) {
                while (__hip_atomic_load(&flag1[tid - 32], __ATOMIC_RELAXED, __HIP_MEMORY_SCOPE_AGENT) < t) {}
            }
        }
        __syncthreads();

        if (layer == 0) {
            #pragma unroll
            for (int i = 0; i < 4; i++) {
                const int idx = tid + i*512;
                u64 v = __hip_atomic_load(&ex1[(size_t)t*2048 + idx], __ATOMIC_RELAXED, __HIP_MEMORY_SCOPE_AGENT);
                *(u64*)&h_s[2*idx] = v;
            }
        } else {
            #pragma unroll
            for (int i = 0; i < 4; i++) {
                const int idx = tid + i*512;
                u64 v1 = __hip_atomic_load(&ex1[(size_t)(t + 1)*2048 + idx], __ATOMIC_RELAXED, __HIP_MEMORY_SCOPE_AGENT);
                u64 v2 = __hip_atomic_load(&ex2[(size_t)t*2048 + idx],       __ATOMIC_RELAXED, __HIP_MEMORY_SCOPE_AGENT);
                *(u64*)&h_s[2*idx]        = v1;
                *(u64*)&h_s[4096 + 2*idx] = v2;
            }
        }
        __syncthreads();

        float acc[16];
        #pragma unroll
        for (int i = 0; i < 16; i++) acc[i] = 0.f;
        if (layer == 0) {
            #pragma unroll
            for (int j = 0; j < 16; j++) {
                const float wv = w[j];
                const float4* hp4 = (const float4*)&h_s[(g*16 + j)*16];
                const float4 h0 = hp4[0], h1v = hp4[1], h2v = hp4[2], h3v = hp4[3];
                acc[0]+=h0.x*wv;  acc[1]+=h0.y*wv;  acc[2]+=h0.z*wv;  acc[3]+=h0.w*wv;
                acc[4]+=h1v.x*wv; acc[5]+=h1v.y*wv; acc[6]+=h1v.z*wv; acc[7]+=h1v.w*wv;
                acc[8]+=h2v.x*wv; acc[9]+=h2v.y*wv; acc[10]+=h2v.z*wv;acc[11]+=h2v.w*wv;
                acc[12]+=h3v.x*wv;acc[13]+=h3v.y*wv;acc[14]+=h3v.w*wv;acc[15]+=h3v.w*wv;
            }
        } else {
            #pragma unroll
            for (int j = 0; j < 32; j++) {
                const float wv = w[j];
                const float4* hp4 = (const float4*)&h_s[(g*32 + j)*16];
                const float4 h0 = hp4[0], h1v = hp4[1], h2v = hp4[2], h3v = hp4[3];
                acc[0]+=h0.x*wv;  acc[1]+=h0.y*wv;  acc[2]+=h0.z*wv;  acc[3]+=h0.w*wv;
                acc[4]+=h1v.x*wv; acc[5]+=h1v.y*wv; acc[6]+=h1v.z*wv; acc[7]+=h1v.w*wv;
                acc[8]+=h2v.x*wv; acc[9]+=h2v.y*wv; acc[10]+=h2v.z*wv;acc[11]+=h2v.w*wv;
                acc[12]+=h3v.x*wv;acc[13]+=h3v.y*wv;acc[14]+=h3v.z*wv;acc[15]+=h3v.w*wv;
            }
        }
        __syncthreads();
        {
            float* rp = &red[g*544 + cc*17];
            #pragma unroll
            for (int b = 0; b < 16; b++) rp[b] = acc[b];
        }
        __syncthreads();
        {
            float zsum = xv;
            #pragma unroll
            for (int g2 = 0; g2 < 16; g2++) zsum += red[g2*544 + cc*17 + g];
            z_s[g*33 + cc] = zsum;
        }
        __syncthreads();
        if (tid < 64) {
            const float zi0 = z_s[wb*33      + wj      ];
            const float zf0 = z_s[wb*33      + 8  + wj ];
            const float zg0 = z_s[wb*33      + 16 + wj ];
            const float zo0 = z_s[wb*33      + 24 + wj ];
            const float zi1 = z_s[(wb+1)*33  + wj      ];
            const float zf1 = z_s[(wb+1)*33  + 8  + wj ];
            const float zg1 = z_s[(wb+1)*33  + 16 + wj ];
            const float zo1 = z_s[(wb+1)*33  + 24 + wj ];
            cst0 = sigm(zf0)*cst0 + sigm(zi0)*tanhf(zg0);
            const float h0 = sigm(zo0)*tanhf(cst0);
            cst1 = sigm(zf1)*cst1 + sigm(zi1)*tanhf(zg1);
            const float h1o = sigm(zo1)*tanhf(cst1);
            union { float f[2]; u64 u; } pk;
            pk.f[0] = h0; pk.f[1] = h1o;
            u64* dst = (u64*)((layer == 0 ? h1_ex : h2_ex)
                              + (size_t)(t + 1)*4096 + (s*8 + wj)*16 + wb);
            __hip_atomic_store(dst, pk.u, __ATOMIC_RELAXED, __HIP_MEMORY_SCOPE_AGENT);
            if (layer == 1) {
                h2_out[((size_t)wb*T_     + t)*LH_ + s*8 + wj] = h0;
                h2_out[((size_t)(wb+1)*T_ + t)*LH_ + s*8 + wj] = h1o;
            }
        }
        asm volatile("s_waitcnt vmcnt(0)" ::: "memory");
        if (tid == 0) {
            int* f = (layer == 0) ? &flag0[s] : &flag1[s];
            __hip_atomic_store(f, t + 1, __ATOMIC_RELAXED, __HIP_MEMORY_SCOPE_AGENT);
        }
    }
}

// ---------------------------------------------------------------------------
// Decoder MLP + softplus, 4 rows per block
// ---------------------------------------------------------------------------
__global__ __launch_bounds__(256) void k_dec(
    const float* __restrict__ h2,
    const float* __restrict__ Wd1, const float* __restrict__ bd1, const float* __restrict__ a1p,
    const float* __restrict__ Wd2, const float* __restrict__ bd2, const float* __restrict__ a2p,
    const float* __restrict__ Wd3, const float* __restrict__ bd3,
    float* __restrict__ oil, float* __restrict__ water)
{
    const int sub = threadIdx.x >> 6;
    const int tid = threadIdx.x & 63;
    const int r   = blockIdx.x*4 + sub;
    __shared__ float hrow[4][256], d1s[4][64], d2s[4][64];
    for (int i = tid; i < 256; i += 64) hrow[sub][i] = h2[(size_t)r*256 + i];
    __syncthreads();
    const float a1 = a1p[0], a2 = a2p[0];
    float acc = bd1[tid];
    for (int k = 0; k < 256; k++) acc += hrow[sub][k]*Wd1[k*64 + tid];
    d1s[sub][tid] = (acc >= 0.f) ? acc : a1*acc;
    __syncthreads();
    acc = bd2[tid];
    for (int k = 0; k < 64; k++) acc += d1s[sub][k]*Wd2[k*64 + tid];
    d2s[sub][tid] = (acc >= 0.f) ? acc : a2*acc;
    __syncthreads();
    if (tid < 20) {
        acc = bd3[tid];
        for (int k = 0; k < 64; k++) acc += d2s[sub][k]*Wd3[k*20 + tid];
        const float spv = (acc > 20.f) ? acc : log1pf(expf(acc));
        const int p = tid >> 1;
        if (tid & 1) water[(size_t)r*10 + p] = spv;
        else         oil  [(size_t)r*10 + p] = spv;
    }
}

// ---------------------------------------------------------------------------
extern "C" void kernel_launch(void* const* d_in, const int* in_sizes, int n_in,
                              void* d_out, int out_size, void* d_ws, size_t ws_size,
                              hipStream_t stream)
{
    const float* pf  = (const float*)d_in[0];
    const float* jf  = (const float*)d_in[1];
    const float* epf = (const float*)d_in[2];
    const float* eif = (const float*)d_in[3];
    const int*   ip2p= (const int*)d_in[4];
    const int*   ii2p= (const int*)d_in[5];
    const float* Wpe = (const float*)d_in[6];  const float* bpe = (const float*)d_in[7];
    const float* Wie = (const float*)d_in[8];  const float* bie = (const float*)d_in[9];
    const float* Wep = (const float*)d_in[10]; const float* bep = (const float*)d_in[11];
    const float* Wei = (const float*)d_in[12]; const float* bei = (const float*)d_in[13];
    const float* Wmp = (const float*)d_in[14]; const float* bmp = (const float*)d_in[15];
    const float* Wmi = (const float*)d_in[16]; const float* bmi = (const float*)d_in[17];
    const float* Wu  = (const float*)d_in[18]; const float* bu  = (const float*)d_in[19];
    const float* Wx0 = (const float*)d_in[20]; const float* Wh0 = (const float*)d_in[21];
    const float* lb0 = (const float*)d_in[22];
    const float* Wx1 = (const float*)d_in[23]; const float* Wh1 = (const float*)d_in[24];
    const float* lb1 = (const float*)d_in[25];
    const float* Wd1 = (const float*)d_in[26]; const float* bd1 = (const float*)d_in[27];
    const float* a1  = (const float*)d_in[28];
    const float* Wd2 = (const float*)d_in[29]; const float* bd2 = (const float*)d_in[30];
    const float* a2  = (const float*)d_in[31];
    const float* Wd3 = (const float*)d_in[32]; const float* bd3 = (const float*)d_in[33];

    float* oil   = (float*)d_out;
    float* water = oil + NPROW_;
    float* emb   = water + NPROW_;

    float* ws    = (float*)d_ws;
    float* X0    = ws;
    float* X1    = X0 + 7475200;
    float* hibuf = X1 + 7475200;
    float* xp0   = hibuf + 5980160;
    float* h1ex  = xp0 + 5980160;
    float* h2ex  = h1ex + 1499136;
    float* h2o   = h2ex + 1499136;
    int*   flag0 = (int*)(h2o + 1495040);
    int*   flag1 = flag0 + 32;
    short* wbf   = (short*)(flag0 + 64);     // 352256 shorts, 16B aligned

    hipMemsetAsync(flag0, 0, 64*sizeof(int), stream);
    hipMemsetAsync(h1ex, 0, 4096*sizeof(float), stream);
    hipMemsetAsync(h2ex, 0, 4096*sizeof(float), stream);

    k_prep<<<(WBF_TOTAL + 511)/512, 512, 0, stream>>>(Wep, Wei, Wmp, Wmi, Wu, wbf);

    k_enc<<<(NPROW_ + NIROW_)/4, 512, 0, stream>>>(pf, jf, Wpe, bpe, Wie, bie, X0, hibuf);

    k_layer<<<BT_, 512, 0, stream>>>(0, X0, hibuf, ip2p, ii2p, epf, eif,
        wbf, bep, bei, bmp, bmi, bu, X1);
    k_layer<<<BT_, 512, 0, stream>>>(1, X1, hibuf, ip2p, ii2p, epf, eif,
        wbf, bep, bei, bmp, bmi, bu, X0);
    k_layer<<<BT_, 512, 0, stream>>>(2, X0, hibuf, ip2p, ii2p, epf, eif,
        wbf, bep, bei, bmp, bmi, bu, emb);

    dim3 gx((BT_ + 31)/32, 8);
    k_gemm_xp<<<gx, 256, 0, stream>>>(emb, Wx0, lb0, xp0);

    k_lstm_scan<<<64, 512, 0, stream>>>(xp0, Wh0, Wx1, Wh1, lb1,
                                        h1ex, h2ex, h2o, flag0, flag1);

    k_dec<<<BT_/4, 256, 0, stream>>>(h2o, Wd1, bd1, a1, Wd2, bd2, a2, Wd3, bd3, oil, water);
}

// Round 5
// 4427.085 us; speedup vs baseline: 2.8130x; 1.1448x over previous
//
#include <hip/hip_runtime.h>

#define B_   16
#define T_   365
#define P_   10
#define NI_  8
#define EP_  90
#define EI_  80
#define PD_  10
#define ID_  8
#define ED_  10
#define H_   128
#define LH_  256
#define DH_  64
#define BT_  (B_*T_)          // 5840
#define NPROW_ (BT_*P_)       // 58400
#define NIROW_ (BT_*NI_)      // 46720

typedef unsigned long long u64;
typedef __attribute__((ext_vector_type(8))) short short8b;   // 8 bf16 (4 VGPRs)
typedef __attribute__((ext_vector_type(4))) float f32x4;     // MFMA C/D

#define MFMA_BF16(a,b,c) __builtin_amdgcn_mfma_f32_16x16x32_bf16(a,b,c,0,0,0)
#define POIS64 0x7F7F7F7F7F7F7F7FULL    // |h|<1 -> 0x7F7F7F7F (3.39e38) unreachable

// fp32 -> bf16 with round-to-nearest-even
__device__ __forceinline__ short f2bf(float f){
    union { float f; unsigned u; } a; a.f = f;
    unsigned r = a.u + 0x7fffu + ((a.u >> 16) & 1u);
    return (short)(r >> 16);
}

// swizzled LDS A-tile addressing: row-major bf16, rowstrideB bytes/row,
// 16B slot index XORed with (row&7) -> 2-way conflict (free) on frag reads
__device__ __forceinline__ short* lds_a(short* base, int row, int kbyte, int rowstrideB){
    return (short*)((char*)base + row*rowstrideB + (kbyte ^ ((row & 7) << 4)));
}
__device__ __forceinline__ void st_bf(short* base, int row, int col, int rowstrideB, short v){
    *(short*)((char*)base + row*rowstrideB + ((2*col) ^ ((row & 7) << 4))) = v;
}

// ---------------------------------------------------------------------------
// Weight prep -> bf16 [N][K] layouts in ws.
// shorts: WencPT@0, WencIT@4096, WtopPT@8192, WtopIT@57344, WbotPT@106496,
//         WbotIT@155648, WuT@204800 (3x[128][384]), WxT@352256 ([1024][1280])
// ---------------------------------------------------------------------------
#define WXT_OFF  352256
#define WBF_TOTAL (352256 + 1310720)
__global__ __launch_bounds__(512) void k_prep(
    const float* __restrict__ Wep, const float* __restrict__ Wei,
    const float* __restrict__ Wmp, const float* __restrict__ Wmi,
    const float* __restrict__ Wu,  const float* __restrict__ Wx0,
    short* __restrict__ wbf)
{
    int i = blockIdx.x*512 + threadIdx.x;
    if (i >= WBF_TOTAL) return;
    short v;
    if (i < 8192) {                          // encoders, K padded 10->32 with zeros
        const float* W = (i < 4096) ? Wep : Wei;
        int j = i & 4095, c = j >> 5, k = j & 31;
        v = (k < PD_) ? f2bf(W[k*H_ + c]) : (short)0;
    } else if (i < 106496) {                 // top halves of Wmp/Wmi
        int j = i - 8192;
        const float* W = (j < 49152) ? Wmp : Wmi;
        j %= 49152;
        int l = j >> 14, r = j & 16383, c = r >> 7, k = r & 127;
        v = f2bf(W[l*2*H_*H_ + k*H_ + c]);
    } else if (i < 204800) {                 // bottom halves
        int j = i - 106496;
        const float* W = (j < 49152) ? Wmp : Wmi;
        j %= 49152;
        int l = j >> 14, r = j & 16383, c = r >> 7, k = r & 127;
        v = f2bf(W[l*2*H_*H_ + (H_ + k)*H_ + c]);
    } else if (i < WXT_OFF) {                // Wu: [384][128] -> [128][384]
        int j = i - 204800;
        int l = j / 49152, r = j % 49152, c = r / 384, k = r % 384;
        v = f2bf(Wu[l*3*H_*H_ + k*H_ + c]);
    } else {                                 // Wx0: [1280][1024] -> [1024][1280]
        int j = i - WXT_OFF;
        int c = j / 1280, k = j % 1280;
        v = f2bf(Wx0[(size_t)k*1024 + c]);
    }
    wbf[i] = v;
}

// ---------------------------------------------------------------------------
// Node encoders: 4 rows per block
// ---------------------------------------------------------------------------
__global__ __launch_bounds__(512) void k_enc(
    const float* __restrict__ pf, const float* __restrict__ jf,
    const float* __restrict__ Wpe, const float* __restrict__ bpe,
    const float* __restrict__ Wie, const float* __restrict__ bie,
    float* __restrict__ hp, float* __restrict__ hi)
{
    const int sub = threadIdx.x >> 7;
    const int j   = threadIdx.x & 127;
    const int r   = blockIdx.x*4 + sub;
    __shared__ float xs[4][16];
    if (r < NPROW_) {
        if (j < PD_) xs[sub][j] = pf[(size_t)r*PD_ + j];
    } else {
        if (j < ID_) xs[sub][j] = jf[(size_t)(r - NPROW_)*ID_ + j];
    }
    __syncthreads();
    if (r < NPROW_) {
        float acc = bpe[j];
        #pragma unroll
        for (int k = 0; k < PD_; k++) acc += xs[sub][k]*Wpe[k*H_ + j];
        hp[(size_t)r*H_ + j] = fmaxf(acc, 0.f);
    } else {
        float acc = bie[j];
        #pragma unroll
        for (int k = 0; k < ID_; k++) acc += xs[sub][k]*Wie[k*H_ + j];
        hi[(size_t)(r - NPROW_)*H_ + j] = fmaxf(acc, 0.f);
    }
}

// ---------------------------------------------------------------------------
// Fused GNN layer, MFMA bf16 (unchanged from round 4 — verified passing)
// ---------------------------------------------------------------------------
__device__ __forceinline__ void edge_phase(
    int bt, int tid, int wv, int ln15, int lg, int NE,
    const float* __restrict__ ef, const int* __restrict__ eidx,
    const short* __restrict__ WencT, const float* __restrict__ benc,
    const short* __restrict__ WbotT,
    const float* __restrict__ hproj_s, float* __restrict__ agg_s,
    short* __restrict__ eenc_A, short* __restrict__ raw_A,
    int* __restrict__ src_s, int* __restrict__ dst_s)
{
    for (int e = tid; e < NE; e += 512) { src_s[e] = eidx[e]; dst_s[e] = eidx[NE + e]; }

    const int c = 16*wv + ln15;
    const float bv = benc[c];

    for (int tb = 0; tb < NE; tb += 32) {
        const int RT = (NE - tb < 32) ? (NE - tb) : 32;
        __syncthreads();
        ((unsigned*)raw_A)[tid] = 0u;
        ((unsigned*)raw_A)[tid + 512] = 0u;
        __syncthreads();
        for (int i = tid; i < RT*ED_; i += 512) {
            const int e = i/ED_, k = i - e*ED_;
            st_bf(raw_A, e, k, 128, f2bf(ef[(size_t)bt*NE*ED_ + (tb + e)*ED_ + k]));
        }
        __syncthreads();
        #pragma unroll
        for (int rtl = 0; rtl < 2; rtl++) {
            short8b a = *(short8b*)lds_a(raw_A, 16*rtl + ln15, lg*16, 128);
            short8b b = *(const short8b*)&WencT[(size_t)c*32 + lg*8];
            f32x4 acc = {0.f,0.f,0.f,0.f};
            acc = MFMA_BF16(a, b, acc);
            #pragma unroll
            for (int j = 0; j < 4; j++) {
                const int row = 16*rtl + lg*4 + j;
                st_bf(eenc_A, row, c, 256, f2bf(fmaxf(acc[j] + bv, 0.f)));
            }
        }
        __syncthreads();
        f32x4 acc0 = {0.f,0.f,0.f,0.f}, acc1 = {0.f,0.f,0.f,0.f};
        #pragma unroll
        for (int kc = 0; kc < 4; kc++) {
            short8b b  = *(const short8b*)&WbotT[(size_t)c*128 + kc*32 + lg*8];
            short8b a0 = *(short8b*)lds_a(eenc_A, ln15,      kc*64 + lg*16, 256);
            short8b a1 = *(short8b*)lds_a(eenc_A, 16 + ln15, kc*64 + lg*16, 256);
            acc0 = MFMA_BF16(a0, b, acc0);
            acc1 = MFMA_BF16(a1, b, acc1);
        }
        #pragma unroll
        for (int j = 0; j < 4; j++) {
            const int el0 = lg*4 + j;
            if (el0 < RT) {
                const int e = tb + el0;
                const float m = fmaxf(acc0[j] + hproj_s[src_s[e]*H_ + c], 0.f);
                atomicAdd(&agg_s[dst_s[e]*H_ + c], m);
            }
            const int el1 = 16 + lg*4 + j;
            if (el1 < RT) {
                const int e = tb + el1;
                const float m = fmaxf(acc1[j] + hproj_s[src_s[e]*H_ + c], 0.f);
                atomicAdd(&agg_s[dst_s[e]*H_ + c], m);
            }
        }
    }
}

__global__ __launch_bounds__(512) void k_layer(
    int l,
    const float* __restrict__ hp_in, const float* __restrict__ hi_g,
    const int* __restrict__ ip2p, const int* __restrict__ ii2p,
    const float* __restrict__ epf, const float* __restrict__ eif,
    const short* __restrict__ wbf,
    const float* __restrict__ bep, const float* __restrict__ bei,
    const float* __restrict__ bmp, const float* __restrict__ bmi,
    const float* __restrict__ bu,
    float* __restrict__ hp_out)
{
    const int bt   = blockIdx.x;
    const int tid  = threadIdx.x;
    const int wv   = tid >> 6;
    const int lane = tid & 63;
    const int ln15 = lane & 15;
    const int lg   = lane >> 4;

    __shared__ short h_s[32*128];
    __shared__ float hpp_s[P_*H_];
    __shared__ float hip_s[NI_*H_];
    __shared__ float aggp_s[P_*H_];
    __shared__ float aggi_s[P_*H_];
    __shared__ short eenc_A[32*128];
    __shared__ short updA[16*384];
    __shared__ int   src_s[EP_], dst_s[EP_];
    short* raw_A = updA;

    const short* WencPT = wbf;
    const short* WencIT = wbf + 4096;
    const short* WtopPT = wbf + 8192   + l*16384;
    const short* WtopIT = wbf + 57344  + l*16384;
    const short* WbotPT = wbf + 106496 + l*16384;
    const short* WbotIT = wbf + 155648 + l*16384;
    const short* WuT    = wbf + 204800 + l*49152;
    const float* bmp_g = bmp + l*H_;
    const float* bmi_g = bmi + l*H_;
    const float* bu_g  = bu  + l*H_;

    for (int i = tid; i < P_*H_; i += 512) {
        const int r = i >> 7, c = i & 127;
        st_bf(h_s, r, c, 256, f2bf(hp_in[(size_t)bt*(P_*H_) + i]));
        aggp_s[i] = 0.f; aggi_s[i] = 0.f;
    }
    for (int i = tid; i < NI_*H_; i += 512) {
        const int r = i >> 7, c = i & 127;
        st_bf(h_s, 16 + r, c, 256, f2bf(hi_g[(size_t)bt*(NI_*H_) + i]));
    }
    __syncthreads();

    {
        f32x4 accp = {0.f,0.f,0.f,0.f}, acci = {0.f,0.f,0.f,0.f};
        const int c = 16*wv + ln15;
        #pragma unroll
        for (int kc = 0; kc < 4; kc++) {
            short8b ap = *(short8b*)lds_a(h_s, ln15,      kc*64 + lg*16, 256);
            short8b bp = *(const short8b*)&WtopPT[(size_t)c*128 + kc*32 + lg*8];
            accp = MFMA_BF16(ap, bp, accp);
            short8b ai = *(short8b*)lds_a(h_s, 16 + ln15, kc*64 + lg*16, 256);
            short8b bi = *(const short8b*)&WtopIT[(size_t)c*128 + kc*32 + lg*8];
            acci = MFMA_BF16(ai, bi, acci);
        }
        const float bpv = bmp_g[c], biv = bmi_g[c];
        #pragma unroll
        for (int j = 0; j < 4; j++) {
            const int r = lg*4 + j;
            if (r < P_)  hpp_s[r*H_ + c] = accp[j] + bpv;
            if (r < NI_) hip_s[r*H_ + c] = acci[j] + biv;
        }
    }
    __syncthreads();

    edge_phase(bt, tid, wv, ln15, lg, EP_, epf, ip2p, WencPT, bep, WbotPT,
               hpp_s, aggp_s, eenc_A, raw_A, src_s, dst_s);
    __syncthreads();
    edge_phase(bt, tid, wv, ln15, lg, EI_, eif, ii2p, WencIT, bei, WbotIT,
               hip_s, aggi_s, eenc_A, raw_A, src_s, dst_s);
    __syncthreads();

    for (int i = tid; i < P_*H_; i += 512) {
        const int r = i >> 7, c = i & 127;
        const short hv = *(short*)((char*)h_s + r*256 + ((2*c) ^ ((r & 7) << 4)));
        st_bf(updA, r, c,        768, hv);
        st_bf(updA, r, 128 + c,  768, f2bf(aggp_s[i]));
        st_bf(updA, r, 256 + c,  768, f2bf(aggi_s[i]));
    }
    __syncthreads();

    {
        f32x4 acc = {0.f,0.f,0.f,0.f};
        const int c = 16*wv + ln15;
        #pragma unroll
        for (int kc = 0; kc < 12; kc++) {
            short8b a = *(short8b*)lds_a(updA, ln15, kc*64 + lg*16, 768);
            short8b b = *(const short8b*)&WuT[(size_t)c*384 + kc*32 + lg*8];
            acc = MFMA_BF16(a, b, acc);
        }
        const float bv = bu_g[c];
        #pragma unroll
        for (int j = 0; j < 4; j++) {
            const int r = lg*4 + j;
            if (r < P_)
                hp_out[(size_t)bt*(P_*H_) + r*H_ + c] = fmaxf(acc[j] + bv, 0.f);
        }
    }
}

// ---------------------------------------------------------------------------
// xproj0 = emb @ Wx0 + lb0, bf16 MFMA. Block 512 (8 waves = 2x4 tiles),
// tile 32 rows x 64 cols, K=1280 in chunks of 64. B from prepped WxT [1024][1280].
// ---------------------------------------------------------------------------
__global__ __launch_bounds__(512) void k_gemm_xp(
    const float* __restrict__ A, const short* __restrict__ WxT,
    const float* __restrict__ bias, float* __restrict__ C)
{
    const int m0 = blockIdx.x*32;
    const int n0 = blockIdx.y*64;
    const int tid = threadIdx.x;
    const int wv = tid >> 6, lane = tid & 63;
    const int ln15 = lane & 15, lg = lane >> 4;
    const int wr = wv >> 2, wc = wv & 3;
    const int c = n0 + wc*16 + ln15;

    __shared__ short As[32*64];      // rowstride 128B, swizzled

    f32x4 acc = {0.f,0.f,0.f,0.f};
    for (int kc0 = 0; kc0 < 1280; kc0 += 64) {
        #pragma unroll
        for (int i = 0; i < 4; i++) {
            const int o = tid + i*512;
            const int row = o >> 6, k = o & 63;
            const int grow = m0 + row;
            const float av = (grow < BT_) ? A[(size_t)grow*1280 + kc0 + k] : 0.f;
            st_bf(As, row, k, 128, f2bf(av));
        }
        __syncthreads();
        #pragma unroll
        for (int h = 0; h < 2; h++) {
            short8b a = *(short8b*)lds_a(As, wr*16 + ln15, h*64 + lg*16, 128);
            short8b b = *(const short8b*)&WxT[(size_t)c*1280 + kc0 + h*32 + lg*8];
            acc = MFMA_BF16(a, b, acc);
        }
        __syncthreads();
    }
    const float bv = bias[c];
    #pragma unroll
    for (int j = 0; j < 4; j++) {
        const int grow = m0 + wr*16 + lg*4 + j;
        if (grow < BT_) C[(size_t)grow*1024 + c] = acc[j] + bv;
    }
}

// ---------------------------------------------------------------------------
// Persistent 2-layer LSTM scan, FLAG-FREE: data IS the signal.
// Exchange buffers pre-poisoned 0x7F7F7F7F (|h|<1 can't collide); producers
// store h-pairs as single atomic u64s; consumers poll data words directly.
// One coherent-latency hop per step instead of three.
// ---------------------------------------------------------------------------
__device__ __forceinline__ float sigm(float x) { return 1.f/(1.f + expf(-x)); }
__device__ __forceinline__ u64 ald(const u64* p){
    return __hip_atomic_load(p, __ATOMIC_RELAXED, __HIP_MEMORY_SCOPE_AGENT);
}

__global__ __launch_bounds__(512) void k_lstm_scan(
    const float* __restrict__ xproj0,
    const float* __restrict__ Wh0,
    const float* __restrict__ Wx1, const float* __restrict__ Wh1,
    const float* __restrict__ lb1,
    float* __restrict__ h1_ex, float* __restrict__ h2_ex,  // [366][256][16]
    float* __restrict__ h2_out)
{
    const int tid   = threadIdx.x;
    const int layer = blockIdx.x >> 5;
    const int s     = blockIdx.x & 31;
    const int cc    = tid & 31;
    const int g     = tid >> 5;
    const int gcol  = (cc >> 3)*256 + s*8 + (cc & 7);

    __shared__ float h_s[8192];
    __shared__ float red[16*544];
    __shared__ float z_s[16*33];

    float w[32];
    if (layer == 0) {
        #pragma unroll
        for (int j = 0; j < 16; j++) w[j] = Wh0[(size_t)(g*16 + j)*1024 + gcol];
    } else {
        #pragma unroll
        for (int j = 0; j < 32; j++) {
            const int k = g*32 + j;
            w[j] = (k < 256) ? Wx1[(size_t)k*1024 + gcol]
                             : Wh1[(size_t)(k - 256)*1024 + gcol];
        }
    }

    const int wj = tid >> 3, wb = (tid & 7)*2;
    float cst0 = 0.f, cst1 = 0.f;
    const float xv_l1 = lb1[gcol];

    const u64* ex1 = (const u64*)h1_ex;
    const u64* ex2 = (const u64*)h2_ex;

    for (int t = 0; t < T_; t++) {
        // x contribution prefetch (independent of exchange)
        float xv;
        if (layer == 0) xv = xproj0[((size_t)g*T_ + t)*1024 + gcol];
        else            xv = xv_l1;

        // poll exchange data directly, stage to LDS
        if (layer == 0) {
            const u64* base = ex1 + (size_t)t*2048;
            u64 v[4];
            #pragma unroll
            for (int i = 0; i < 4; i++) v[i] = ald(base + tid + i*512);
            for (;;) {
                bool ok = true;
                #pragma unroll
                for (int i = 0; i < 4; i++)
                    if (v[i] == POIS64) { v[i] = ald(base + tid + i*512); ok = false; }
                if (ok) break;
            }
            #pragma unroll
            for (int i = 0; i < 4; i++) *(u64*)&h_s[2*(tid + i*512)] = v[i];
        } else {
            const u64* b1 = ex1 + (size_t)(t + 1)*2048;
            const u64* b2 = ex2 + (size_t)t*2048;
            u64 v1[4], v2[4];
            #pragma unroll
            for (int i = 0; i < 4; i++) { v1[i] = ald(b1 + tid + i*512); v2[i] = ald(b2 + tid + i*512); }
            for (;;) {
                bool ok = true;
                #pragma unroll
                for (int i = 0; i < 4; i++) {
                    if (v1[i] == POIS64) { v1[i] = ald(b1 + tid + i*512); ok = false; }
                    if (v2[i] == POIS64) { v2[i] = ald(b2 + tid + i*512); ok = false; }
                }
                if (ok) break;
            }
            #pragma unroll
            for (int i = 0; i < 4; i++) {
                *(u64*)&h_s[2*(tid + i*512)]        = v1[i];
                *(u64*)&h_s[4096 + 2*(tid + i*512)] = v2[i];
            }
        }
        __syncthreads();                                   // B1: h_s ready

        // gate GEMM: acc[b] = sum_j w[j] * h[k(j)][b]
        float acc[16];
        #pragma unroll
        for (int i = 0; i < 16; i++) acc[i] = 0.f;
        if (layer == 0) {
            #pragma unroll
            for (int j = 0; j < 16; j++) {
                const float wv = w[j];
                const float4* hp4 = (const float4*)&h_s[(g*16 + j)*16];
                const float4 h0 = hp4[0], h1v = hp4[1], h2v = hp4[2], h3v = hp4[3];
                acc[0]+=h0.x*wv;  acc[1]+=h0.y*wv;  acc[2]+=h0.z*wv;  acc[3]+=h0.w*wv;
                acc[4]+=h1v.x*wv; acc[5]+=h1v.y*wv; acc[6]+=h1v.z*wv; acc[7]+=h1v.w*wv;
                acc[8]+=h2v.x*wv; acc[9]+=h2v.y*wv; acc[10]+=h2v.z*wv;acc[11]+=h2v.w*wv;
                acc[12]+=h3v.x*wv;acc[13]+=h3v.y*wv;acc[14]+=h3v.z*wv;acc[15]+=h3v.w*wv;
            }
        } else {
            #pragma unroll
            for (int j = 0; j < 32; j++) {
                const float wv = w[j];
                const float4* hp4 = (const float4*)&h_s[(g*32 + j)*16];
                const float4 h0 = hp4[0], h1v = hp4[1], h2v = hp4[2], h3v = hp4[3];
                acc[0]+=h0.x*wv;  acc[1]+=h0.y*wv;  acc[2]+=h0.z*wv;  acc[3]+=h0.w*wv;
                acc[4]+=h1v.x*wv; acc[5]+=h1v.y*wv; acc[6]+=h1v.z*wv; acc[7]+=h1v.w*wv;
                acc[8]+=h2v.x*wv; acc[9]+=h2v.y*wv; acc[10]+=h2v.z*wv;acc[11]+=h2v.w*wv;
                acc[12]+=h3v.x*wv;acc[13]+=h3v.y*wv;acc[14]+=h3v.z*wv;acc[15]+=h3v.w*wv;
            }
        }
        // partials -> LDS (unique slots per thread)
        {
            float* rp = &red[g*544 + cc*17];
            #pragma unroll
            for (int b = 0; b < 16; b++) rp[b] = acc[b];
        }
        __syncthreads();                                   // B2: red ready

        {
            float zsum = xv;
            #pragma unroll
            for (int g2 = 0; g2 < 16; g2++) zsum += red[g2*544 + cc*17 + g];
            z_s[g*33 + cc] = zsum;
        }
        __syncthreads();                                   // B3: z ready

        // cell update: wave 0; thread owns (h-col wj, batches wb, wb+1)
        if (tid < 64) {
            const float zi0 = z_s[wb*33      + wj      ];
            const float zf0 = z_s[wb*33      + 8  + wj ];
            const float zg0 = z_s[wb*33      + 16 + wj ];
            const float zo0 = z_s[wb*33      + 24 + wj ];
            const float zi1 = z_s[(wb+1)*33  + wj      ];
            const float zf1 = z_s[(wb+1)*33  + 8  + wj ];
            const float zg1 = z_s[(wb+1)*33  + 16 + wj ];
            const float zo1 = z_s[(wb+1)*33  + 24 + wj ];
            cst0 = sigm(zf0)*cst0 + sigm(zi0)*tanhf(zg0);
            const float h0 = sigm(zo0)*tanhf(cst0);
            cst1 = sigm(zf1)*cst1 + sigm(zi1)*tanhf(zg1);
            const float h1o = sigm(zo1)*tanhf(cst1);
            union { float f[2]; u64 u; } pk;
            pk.f[0] = h0; pk.f[1] = h1o;
            u64* dst = (u64*)((layer == 0 ? h1_ex : h2_ex)
                              + (size_t)(t + 1)*4096 + (s*8 + wj)*16 + wb);
            __hip_atomic_store(dst, pk.u, __ATOMIC_RELAXED, __HIP_MEMORY_SCOPE_AGENT);
            if (layer == 1) {
                h2_out[((size_t)wb*T_     + t)*LH_ + s*8 + wj] = h0;
                h2_out[((size_t)(wb+1)*T_ + t)*LH_ + s*8 + wj] = h1o;
            }
        }
        // no drain, no flag: the data store is the signal
    }
}

// ---------------------------------------------------------------------------
// Decoder MLP + softplus, 4 rows per block
// ---------------------------------------------------------------------------
__global__ __launch_bounds__(256) void k_dec(
    const float* __restrict__ h2,
    const float* __restrict__ Wd1, const float* __restrict__ bd1, const float* __restrict__ a1p,
    const float* __restrict__ Wd2, const float* __restrict__ bd2, const float* __restrict__ a2p,
    const float* __restrict__ Wd3, const float* __restrict__ bd3,
    float* __restrict__ oil, float* __restrict__ water)
{
    const int sub = threadIdx.x >> 6;
    const int tid = threadIdx.x & 63;
    const int r   = blockIdx.x*4 + sub;
    __shared__ float hrow[4][256], d1s[4][64], d2s[4][64];
    for (int i = tid; i < 256; i += 64) hrow[sub][i] = h2[(size_t)r*256 + i];
    __syncthreads();
    const float a1 = a1p[0], a2 = a2p[0];
    float acc = bd1[tid];
    for (int k = 0; k < 256; k++) acc += hrow[sub][k]*Wd1[k*64 + tid];
    d1s[sub][tid] = (acc >= 0.f) ? acc : a1*acc;
    __syncthreads();
    acc = bd2[tid];
    for (int k = 0; k < 64; k++) acc += d1s[sub][k]*Wd2[k*64 + tid];
    d2s[sub][tid] = (acc >= 0.f) ? acc : a2*acc;
    __syncthreads();
    if (tid < 20) {
        acc = bd3[tid];
        for (int k = 0; k < 64; k++) acc += d2s[sub][k]*Wd3[k*20 + tid];
        const float spv = (acc > 20.f) ? acc : log1pf(expf(acc));
        const int p = tid >> 1;
        if (tid & 1) water[(size_t)r*10 + p] = spv;
        else         oil  [(size_t)r*10 + p] = spv;
    }
}

// ---------------------------------------------------------------------------
extern "C" void kernel_launch(void* const* d_in, const int* in_sizes, int n_in,
                              void* d_out, int out_size, void* d_ws, size_t ws_size,
                              hipStream_t stream)
{
    const float* pf  = (const float*)d_in[0];
    const float* jf  = (const float*)d_in[1];
    const float* epf = (const float*)d_in[2];
    const float* eif = (const float*)d_in[3];
    const int*   ip2p= (const int*)d_in[4];
    const int*   ii2p= (const int*)d_in[5];
    const float* Wpe = (const float*)d_in[6];  const float* bpe = (const float*)d_in[7];
    const float* Wie = (const float*)d_in[8];  const float* bie = (const float*)d_in[9];
    const float* Wep = (const float*)d_in[10]; const float* bep = (const float*)d_in[11];
    const float* Wei = (const float*)d_in[12]; const float* bei = (const float*)d_in[13];
    const float* Wmp = (const float*)d_in[14]; const float* bmp = (const float*)d_in[15];
    const float* Wmi = (const float*)d_in[16]; const float* bmi = (const float*)d_in[17];
    const float* Wu  = (const float*)d_in[18]; const float* bu  = (const float*)d_in[19];
    const float* Wx0 = (const float*)d_in[20]; const float* Wh0 = (const float*)d_in[21];
    const float* lb0 = (const float*)d_in[22];
    const float* Wx1 = (const float*)d_in[23]; const float* Wh1 = (const float*)d_in[24];
    const float* lb1 = (const float*)d_in[25];
    const float* Wd1 = (const float*)d_in[26]; const float* bd1 = (const float*)d_in[27];
    const float* a1  = (const float*)d_in[28];
    const float* Wd2 = (const float*)d_in[29]; const float* bd2 = (const float*)d_in[30];
    const float* a2  = (const float*)d_in[31];
    const float* Wd3 = (const float*)d_in[32]; const float* bd3 = (const float*)d_in[33];

    float* oil   = (float*)d_out;
    float* water = oil + NPROW_;
    float* emb   = water + NPROW_;

    float* ws    = (float*)d_ws;
    float* X0    = ws;
    float* X1    = X0 + 7475200;
    float* hibuf = X1 + 7475200;
    float* xp0   = hibuf + 5980160;
    float* h1ex  = xp0 + 5980160;            // 366*4096 = 1,499,136 floats
    float* h2ex  = h1ex + 1499136;
    float* h2o   = h2ex + 1499136;
    short* wbf   = (short*)(h2o + 1495040);  // WBF_TOTAL shorts, 16B aligned

    // poison exchange buffers (0x7F7F7F7F = 3.39e38, unreachable for |h|<1),
    // then zero the t=0 init slices
    hipMemsetAsync(h1ex, 0x7F, 1499136*sizeof(float), stream);
    hipMemsetAsync(h2ex, 0x7F, 1499136*sizeof(float), stream);
    hipMemsetAsync(h1ex, 0, 4096*sizeof(float), stream);
    hipMemsetAsync(h2ex, 0, 4096*sizeof(float), stream);

    k_prep<<<(WBF_TOTAL + 511)/512, 512, 0, stream>>>(Wep, Wei, Wmp, Wmi, Wu, Wx0, wbf);

    k_enc<<<(NPROW_ + NIROW_)/4, 512, 0, stream>>>(pf, jf, Wpe, bpe, Wie, bie, X0, hibuf);

    k_layer<<<BT_, 512, 0, stream>>>(0, X0, hibuf, ip2p, ii2p, epf, eif,
        wbf, bep, bei, bmp, bmi, bu, X1);
    k_layer<<<BT_, 512, 0, stream>>>(1, X1, hibuf, ip2p, ii2p, epf, eif,
        wbf, bep, bei, bmp, bmi, bu, X0);
    k_layer<<<BT_, 512, 0, stream>>>(2, X0, hibuf, ip2p, ii2p, epf, eif,
        wbf, bep, bei, bmp, bmi, bu, emb);

    dim3 gx((BT_ + 31)/32, 1024/64);
    k_gemm_xp<<<gx, 512, 0, stream>>>(emb, wbf + WXT_OFF, lb0, xp0);

    k_lstm_scan<<<64, 512, 0, stream>>>(xp0, Wh0, Wx1, Wh1, lb1, h1ex, h2ex, h2o);

    k_dec<<<BT_/4, 256, 0, stream>>>(h2o, Wd1, bd1, a1, Wd2, bd2, a2, Wd3, bd3, oil, water);
}